// Round 1
// baseline (599.431 us; speedup 1.0000x reference)
//
#include <hip/hip_runtime.h>
#include <hip/hip_bf16.h>
#include <math.h>

#define HH 56
#define WW 56
#define HW 3136
#define CC 128
#define NHEAD 4
#define CHD 32
#define RP 111
#define SCALE 0.17677669529663687f   // 32^-0.5
#define NCHUNK 8
#define CHUNK 392                    // 3136/8
#define NT 56                        // n-tile inside a chunk; 392 = 7*56

// ---- ws layout (float offsets) ----
#define OFF_RWO  0u                          // 3136*2
#define OFF_KT   8192u                       // 4*3136*32 = 401408, layout (h, n, c)
#define OFF_VT   (8192u + 401408u)
#define OFF_ATT  (8192u + 2u*401408u)        // 128 x 3136
#define OFF_KWT  (8192u + 3u*401408u)        // 128x128 transposed
#define OFF_VWT  (OFF_KWT + 16384u)
#define OFF_OWT  (OFF_KWT + 32768u)
#define OFF_XT   (OFF_KWT + 49152u)          // 3136 x 128  (p, c)
#define OFF_PART (OFF_XT + 401408u)          // 4*3136*8*34

// ---------------- transpose 128x128 weights (3 of them) ----------------
__global__ void tw_kernel(const float* __restrict__ a, const float* __restrict__ b,
                          const float* __restrict__ c,
                          float* __restrict__ at, float* __restrict__ bt, float* __restrict__ ct) {
    const float* src = (blockIdx.y == 0) ? a : (blockIdx.y == 1) ? b : c;
    float* dst       = (blockIdx.y == 0) ? at : (blockIdx.y == 1) ? bt : ct;
    int i = blockIdx.x * 256 + threadIdx.x;      // 16384 total
    int o = i >> 7, cc = i & 127;
    dst[cc * 128 + o] = src[i];
}

// ---------------- transpose x: (c, p) -> (p, c) ----------------
__global__ void tx_kernel(const float* __restrict__ x, float* __restrict__ xT) {
    int i = blockIdx.x * 256 + threadIdx.x;      // 401408 = 1568*256
    int c = i / HW, p = i % HW;
    xT[p * 128 + c] = x[i];
}

// ---------------- offset field: dwconv3x3 + LN + GELU + 1x1 -> rwo ----------------
__global__ __launch_bounds__(128) void offset_kernel(
    const float* __restrict__ query, const float* __restrict__ dww, const float* __restrict__ dwb,
    const float* __restrict__ lnw, const float* __restrict__ lnb, const float* __restrict__ pww,
    float* __restrict__ rwo) {
    int p = blockIdx.x;
    int c = threadIdx.x;
    int h = p / WW, w = p % WW;

    float t = dwb[c];
#pragma unroll
    for (int ky = 0; ky < 3; ky++) {
        int yy = h + ky - 1;
        if ((unsigned)yy < (unsigned)HH) {
#pragma unroll
            for (int kx = 0; kx < 3; kx++) {
                int xx = w + kx - 1;
                if ((unsigned)xx < (unsigned)WW)
                    t += query[c * HW + yy * WW + xx] * dww[c * 9 + ky * 3 + kx];
            }
        }
    }

    __shared__ float red[128];
    // mean
    red[c] = t; __syncthreads();
    for (int s = 64; s > 0; s >>= 1) { if (c < s) red[c] += red[c + s]; __syncthreads(); }
    float mu = red[0] * (1.f / 128.f); __syncthreads();
    // var
    float d = t - mu;
    red[c] = d * d; __syncthreads();
    for (int s = 64; s > 0; s >>= 1) { if (c < s) red[c] += red[c + s]; __syncthreads(); }
    float var = red[0] * (1.f / 128.f); __syncthreads();

    float tn = d / sqrtf(var + 1e-5f) * lnw[c] + lnb[c];
    float g = 0.5f * tn * (1.f + erff(tn * 0.70710678118654752f));

    // two 1x1 dots
    red[c] = g * pww[c]; __syncthreads();
    for (int s = 64; s > 0; s >>= 1) { if (c < s) red[c] += red[c + s]; __syncthreads(); }
    float offy = red[0]; __syncthreads();
    red[c] = g * pww[128 + c]; __syncthreads();
    for (int s = 64; s > 0; s >>= 1) { if (c < s) red[c] += red[c + s]; __syncthreads(); }
    float offx = red[0];

    if (c == 0) {
        offy = tanhf(offy) * (0.5f / 55.f);
        offx = tanhf(offx) * (0.5f / 55.f);
        rwo[p * 2]     = offy + ((float)h * (2.f / 55.f) - 1.f);   // y
        rwo[p * 2 + 1] = offx + ((float)w * (2.f / 55.f) - 1.f);   // x
    }
}

// ---------------- bilinear sample + k/v projection ----------------
__global__ __launch_bounds__(128) void sample_kv_kernel(
    const float* __restrict__ xT, const float* __restrict__ rwo,
    const float* __restrict__ kwT, const float* __restrict__ vwT,
    const float* __restrict__ kb, const float* __restrict__ vb,
    float* __restrict__ kT, float* __restrict__ vT) {
    int n0 = blockIdx.x * 32;
    int tid = threadIdx.x;

    __shared__ float xs[128 * 33];
    __shared__ int   cidx[32][4];
    __shared__ float cw[32][4];

    if (tid < 32) {
        int n = n0 + tid;
        float gy = rwo[2 * n], gx = rwo[2 * n + 1];
        float fx = (gx + 1.f) * 27.5f;    // 0.5*(56-1)
        float fy = (gy + 1.f) * 27.5f;
        float x0f = floorf(fx), y0f = floorf(fy);
        float wx = fx - x0f, wy = fy - y0f;
        int x0 = (int)x0f, y0 = (int)y0f;
#pragma unroll
        for (int k = 0; k < 4; k++) {
            int xi = x0 + (k & 1), yi = y0 + (k >> 1);
            float wgt = ((k & 1) ? wx : 1.f - wx) * ((k >> 1) ? wy : 1.f - wy);
            bool v = (xi >= 0) && (xi < WW) && (yi >= 0) && (yi < HH);
            cidx[tid][k] = min(max(yi, 0), HH - 1) * WW + min(max(xi, 0), WW - 1);
            cw[tid][k] = v ? wgt : 0.f;
        }
    }
    __syncthreads();

    // each thread = channel c; sample 32 columns
    for (int j = 0; j < 32; j++) {
        float s = cw[j][0] * xT[cidx[j][0] * 128 + tid]
                + cw[j][1] * xT[cidx[j][1] * 128 + tid]
                + cw[j][2] * xT[cidx[j][2] * 128 + tid]
                + cw[j][3] * xT[cidx[j][3] * 128 + tid];
        xs[tid * 33 + j] = s;
    }
    __syncthreads();

    // each thread = output row o; GEMM over 128 channels for 32 columns
    float ak[32], av[32];
#pragma unroll
    for (int j = 0; j < 32; j++) { ak[j] = 0.f; av[j] = 0.f; }
    for (int c = 0; c < 128; c++) {
        float wk = kwT[c * 128 + tid];
        float wv = vwT[c * 128 + tid];
#pragma unroll
        for (int j = 0; j < 32; j++) {
            float xv = xs[c * 33 + j];
            ak[j] += wk * xv;
            av[j] += wv * xv;
        }
    }
    float kbv = kb[tid], vbv = vb[tid];
    int hh = tid >> 5, ch = tid & 31;
#pragma unroll
    for (int j = 0; j < 32; j++) {
        int addr = (hh * HW + n0 + j) * 32 + ch;
        kT[addr] = ak[j] + kbv;
        vT[addr] = av[j] + vbv;
    }
}

// ---------------- flash attention partials ----------------
__global__ __launch_bounds__(256) void attn_partial_kernel(
    const float* __restrict__ query, const float* __restrict__ kT, const float* __restrict__ vT,
    const float* __restrict__ rwo, const float* __restrict__ rpe, float* __restrict__ part) {
    const int chunk = blockIdx.x;    // 0..7
    const int mt = blockIdx.y;       // 0..12
    const int hd = blockIdx.z;       // 0..3
    const int tid = threadIdx.x;
    const int m = mt * 256 + tid;
    const bool mvalid = (m < HW);
    const int mm = mvalid ? m : 0;

    __shared__ float kt[NT * 32];
    __shared__ float vt[NT * 32];
    __shared__ float rw[NT * 2];

    float q[32];
#pragma unroll
    for (int c = 0; c < 32; c++) q[c] = query[(hd * 32 + c) * HW + mm];

    float ym = (float)(mm / WW) * (2.f / 55.f) - 1.f;
    float xm = (float)(mm % WW) * (2.f / 55.f) - 1.f;
    const float* rpeh = rpe + hd * RP * RP;

    float maxv = -INFINITY, ssum = 0.f;
    float acc[32];
#pragma unroll
    for (int c = 0; c < 32; c++) acc[c] = 0.f;

    for (int t = 0; t < 7; t++) {
        int n0 = chunk * CHUNK + t * NT;
        const float* kg = kT + (size_t)(hd * HW + n0) * 32;
        const float* vg = vT + (size_t)(hd * HW + n0) * 32;
        __syncthreads();
        for (int e = tid; e < NT * 32; e += 256) { kt[e] = kg[e]; vt[e] = vg[e]; }
        for (int e = tid; e < NT * 2; e += 256)  rw[e] = rwo[n0 * 2 + e];
        __syncthreads();

        for (int j = 0; j < NT; j++) {
            // QK dot
            float dot = 0.f;
            const float4* k4 = (const float4*)(kt + j * 32);
#pragma unroll
            for (int c4 = 0; c4 < 8; c4++) {
                float4 kv = k4[c4];
                dot += q[c4 * 4 + 0] * kv.x + q[c4 * 4 + 1] * kv.y
                     + q[c4 * 4 + 2] * kv.z + q[c4 * 4 + 3] * kv.w;
            }
            // rpe bias: bilinear sample at ((qm - rwo_n)*0.5) mapped to 111x111, align_corners
            float yn = rw[j * 2], xn = rw[j * 2 + 1];
            float fx = ((xm - xn) * 0.5f + 1.f) * 55.f;   // 0.5*(111-1)
            float fy = ((ym - yn) * 0.5f + 1.f) * 55.f;
            float x0f = floorf(fx), y0f = floorf(fy);
            float wx = fx - x0f, wy = fy - y0f;
            int x0 = (int)x0f, y0 = (int)y0f;
            int x1 = x0 + 1, y1 = y0 + 1;
            bool vx0 = (unsigned)x0 < (unsigned)RP, vx1 = (unsigned)x1 < (unsigned)RP;
            bool vy0 = (unsigned)y0 < (unsigned)RP, vy1 = (unsigned)y1 < (unsigned)RP;
            int cx0 = min(max(x0, 0), RP - 1), cx1 = min(max(x1, 0), RP - 1);
            int cy0 = min(max(y0, 0), RP - 1), cy1 = min(max(y1, 0), RP - 1);
            float w00 = (1.f - wx) * (1.f - wy) * ((vx0 && vy0) ? 1.f : 0.f);
            float w10 = wx * (1.f - wy) * ((vx1 && vy0) ? 1.f : 0.f);
            float w01 = (1.f - wx) * wy * ((vx0 && vy1) ? 1.f : 0.f);
            float w11 = wx * wy * ((vx1 && vy1) ? 1.f : 0.f);
            float bias = w00 * rpeh[cy0 * RP + cx0] + w10 * rpeh[cy0 * RP + cx1]
                       + w01 * rpeh[cy1 * RP + cx0] + w11 * rpeh[cy1 * RP + cx1];

            float logit = dot * SCALE + bias;
            float pr;
            if (logit > maxv) {
                float corr = __expf(maxv - logit);
                ssum *= corr;
#pragma unroll
                for (int c = 0; c < 32; c++) acc[c] *= corr;
                maxv = logit;
                pr = 1.f;
            } else {
                pr = __expf(logit - maxv);
            }
            ssum += pr;
            const float4* v4 = (const float4*)(vt + j * 32);
#pragma unroll
            for (int c4 = 0; c4 < 8; c4++) {
                float4 vv = v4[c4];
                acc[c4 * 4 + 0] += pr * vv.x;
                acc[c4 * 4 + 1] += pr * vv.y;
                acc[c4 * 4 + 2] += pr * vv.z;
                acc[c4 * 4 + 3] += pr * vv.w;
            }
        }
    }

    if (mvalid) {
        float* pb = part + ((size_t)(hd * HW + m) * NCHUNK + chunk) * 34;
        pb[0] = maxv;
        pb[1] = ssum;
#pragma unroll
        for (int c = 0; c < 32; c++) pb[2 + c] = acc[c];
    }
}

// ---------------- combine partials -> att_out (128 x 3136) ----------------
__global__ __launch_bounds__(256) void combine_kernel(const float* __restrict__ part,
                                                      float* __restrict__ att) {
    int idx = blockIdx.x * 256 + threadIdx.x;
    if (idx >= NHEAD * HW) return;
    int hd = idx / HW, m = idx % HW;
    const float* pb = part + (size_t)(hd * HW + m) * NCHUNK * 34;

    float M = -INFINITY;
#pragma unroll
    for (int k = 0; k < NCHUNK; k++) M = fmaxf(M, pb[k * 34]);
    float ek[NCHUNK];
    float tot = 0.f;
#pragma unroll
    for (int k = 0; k < NCHUNK; k++) {
        ek[k] = __expf(pb[k * 34] - M);
        tot += pb[k * 34 + 1] * ek[k];
    }
    float inv = 1.f / tot;
#pragma unroll
    for (int c = 0; c < 32; c++) {
        float a = 0.f;
#pragma unroll
        for (int k = 0; k < NCHUNK; k++) a += pb[k * 34 + 2 + c] * ek[k];
        att[(hd * 32 + c) * HW + m] = a * inv;
    }
}

// ---------------- output 1x1 conv ----------------
__global__ __launch_bounds__(128) void out_conv_kernel(const float* __restrict__ att,
                                                       const float* __restrict__ owT,
                                                       const float* __restrict__ ob,
                                                       float* __restrict__ out) {
    int m0 = blockIdx.x * 32;
    int tid = threadIdx.x;
    __shared__ float at[128 * 33];
    for (int e = tid; e < 4096; e += 128) {
        int c = e >> 5, j = e & 31;
        at[c * 33 + j] = att[c * HW + m0 + j];
    }
    __syncthreads();

    float acc[32];
#pragma unroll
    for (int j = 0; j < 32; j++) acc[j] = 0.f;
    for (int c = 0; c < 128; c++) {
        float w = owT[c * 128 + tid];
#pragma unroll
        for (int j = 0; j < 32; j++) acc[j] += w * at[c * 33 + j];
    }
    float b = ob[tid];
#pragma unroll
    for (int j = 0; j < 32; j++) out[tid * HW + m0 + j] = acc[j] + b;
}

extern "C" void kernel_launch(void* const* d_in, const int* in_sizes, int n_in,
                              void* d_out, int out_size, void* d_ws, size_t ws_size,
                              hipStream_t stream) {
    const float* x     = (const float*)d_in[0];
    const float* query = (const float*)d_in[1];
    const float* dww   = (const float*)d_in[2];
    const float* dwb   = (const float*)d_in[3];
    const float* lnw   = (const float*)d_in[4];
    const float* lnb   = (const float*)d_in[5];
    const float* pww   = (const float*)d_in[6];
    const float* kw    = (const float*)d_in[7];
    const float* kb    = (const float*)d_in[8];
    const float* vw    = (const float*)d_in[9];
    const float* vb    = (const float*)d_in[10];
    const float* ow    = (const float*)d_in[11];
    const float* ob    = (const float*)d_in[12];
    const float* rpe   = (const float*)d_in[13];
    float* out = (float*)d_out;
    float* ws  = (float*)d_ws;

    tw_kernel<<<dim3(64, 3), 256, 0, stream>>>(kw, vw, ow,
                                               ws + OFF_KWT, ws + OFF_VWT, ws + OFF_OWT);
    tx_kernel<<<1568, 256, 0, stream>>>(x, ws + OFF_XT);
    offset_kernel<<<HW, 128, 0, stream>>>(query, dww, dwb, lnw, lnb, pww, ws + OFF_RWO);
    sample_kv_kernel<<<98, 128, 0, stream>>>(ws + OFF_XT, ws + OFF_RWO,
                                             ws + OFF_KWT, ws + OFF_VWT, kb, vb,
                                             ws + OFF_KT, ws + OFF_VT);
    attn_partial_kernel<<<dim3(NCHUNK, 13, NHEAD), 256, 0, stream>>>(
        query, ws + OFF_KT, ws + OFF_VT, ws + OFF_RWO, rpe, ws + OFF_PART);
    combine_kernel<<<49, 256, 0, stream>>>(ws + OFF_PART, ws + OFF_ATT);
    out_conv_kernel<<<98, 128, 0, stream>>>(ws + OFF_ATT, ws + OFF_OWT, ob, out);
}

// Round 2
// 315.291 us; speedup vs baseline: 1.9012x; 1.9012x over previous
//
#include <hip/hip_runtime.h>
#include <hip/hip_bf16.h>
#include <math.h>

#define HH 56
#define WW 56
#define HW 3136
#define NHEAD 4
#define RP 111
#define SCALE 0.17677669529663687f   // 32^-0.5
#define GHW 12544                    // NHEAD*HW

// ---- ws layout (float offsets) ----
#define OFF_RWO  0u                          // 3136*2 = 6272 (pad to 8192)
#define OFF_KT   8192u                       // 4*3136*32 = 401408, layout (h, n, c)
#define OFF_VT   (OFF_KT + 401408u)
#define OFF_ATT  (OFF_VT + 401408u)          // 128 x 3136
#define OFF_KWT  (OFF_ATT + 401408u)         // 128x128 transposed
#define OFF_VWT  (OFF_KWT + 16384u)
#define OFF_OWT  (OFF_VWT + 16384u)
#define OFF_XT   (OFF_OWT + 16384u)          // 3136 x 128  (p, c)
#define OFF_QT   (OFF_XT + 401408u)          // 3136 x 128  (p, c)
#define OFF_PART (OFF_QT + 401408u)          // nchunk * 34 * GHW, field-major

// ---------------- transpose 128x128 weights (3 of them) ----------------
__global__ void tw_kernel(const float* __restrict__ a, const float* __restrict__ b,
                          const float* __restrict__ c,
                          float* __restrict__ at, float* __restrict__ bt, float* __restrict__ ct) {
    const float* src = (blockIdx.y == 0) ? a : (blockIdx.y == 1) ? b : c;
    float* dst       = (blockIdx.y == 0) ? at : (blockIdx.y == 1) ? bt : ct;
    int i = blockIdx.x * 256 + threadIdx.x;      // 16384 total
    int o = i >> 7, cc = i & 127;
    dst[cc * 128 + o] = src[i];
}

// ---------------- tiled transpose (c, p) -> (p, c) for x and query ----------------
__global__ __launch_bounds__(256) void tx_kernel(const float* __restrict__ x,
                                                 const float* __restrict__ query,
                                                 float* __restrict__ xT, float* __restrict__ qT) {
    const float* src = blockIdx.z ? query : x;
    float* dst       = blockIdx.z ? qT : xT;
    __shared__ float tile[32][33];
    int pt = blockIdx.x * 32;     // 98 tiles
    int ct = blockIdx.y * 32;     // 4 tiles
    int jj = threadIdx.x & 31, ii = threadIdx.x >> 5;   // ii 0..7
#pragma unroll
    for (int r = 0; r < 4; r++)
        tile[ii + r * 8][jj] = src[(ct + ii + r * 8) * HW + pt + jj];
    __syncthreads();
#pragma unroll
    for (int r = 0; r < 4; r++)
        dst[(pt + ii + r * 8) * 128 + ct + jj] = tile[jj][ii + r * 8];
}

// ---------------- wave/block reduction helpers ----------------
__device__ __forceinline__ float wave_sum(float v) {
#pragma unroll
    for (int o = 1; o < 64; o <<= 1) v += __shfl_xor(v, o);
    return v;
}

// ---------------- offset field: dwconv3x3 + LN + GELU + 1x1 -> rwo ----------------
__global__ __launch_bounds__(128) void offset_kernel(
    const float* __restrict__ qT, const float* __restrict__ dww, const float* __restrict__ dwb,
    const float* __restrict__ lnw, const float* __restrict__ lnb, const float* __restrict__ pww,
    float* __restrict__ rwo) {
    int p = blockIdx.x;
    int c = threadIdx.x;
    int h = p / WW, w = p % WW;

    float t = dwb[c];
#pragma unroll
    for (int ky = 0; ky < 3; ky++) {
        int yy = h + ky - 1;
        if ((unsigned)yy < (unsigned)HH) {
#pragma unroll
            for (int kx = 0; kx < 3; kx++) {
                int xx = w + kx - 1;
                if ((unsigned)xx < (unsigned)WW)
                    t += qT[(yy * WW + xx) * 128 + c] * dww[c * 9 + ky * 3 + kx];
            }
        }
    }

    __shared__ float sred[4];
    int wid = c >> 6, lane0 = ((c & 63) == 0);

    float s = wave_sum(t);
    if (lane0) sred[wid] = s;
    __syncthreads();
    float mu = (sred[0] + sred[1]) * (1.f / 128.f);
    float d = t - mu;
    __syncthreads();
    s = wave_sum(d * d);
    if (lane0) sred[wid] = s;
    __syncthreads();
    float var = (sred[0] + sred[1]) * (1.f / 128.f);

    float tn = d / sqrtf(var + 1e-5f) * lnw[c] + lnb[c];
    float g = 0.5f * tn * (1.f + erff(tn * 0.70710678118654752f));

    float sy = wave_sum(g * pww[c]);
    float sx = wave_sum(g * pww[128 + c]);
    __syncthreads();
    if (lane0) { sred[wid] = sy; sred[2 + wid] = sx; }
    __syncthreads();
    if (c == 0) {
        float offy = tanhf(sred[0] + sred[1]) * (0.5f / 55.f);
        float offx = tanhf(sred[2] + sred[3]) * (0.5f / 55.f);
        rwo[p * 2]     = offy + ((float)h * (2.f / 55.f) - 1.f);   // y
        rwo[p * 2 + 1] = offx + ((float)w * (2.f / 55.f) - 1.f);   // x
    }
}

// ---------------- bilinear sample + k/v projection (8 cols / block) ----------------
__global__ __launch_bounds__(128) void sample_kv_kernel(
    const float* __restrict__ xT, const float* __restrict__ rwo,
    const float* __restrict__ kwT, const float* __restrict__ vwT,
    const float* __restrict__ kb, const float* __restrict__ vb,
    float* __restrict__ kT, float* __restrict__ vT) {
    int n0 = blockIdx.x * 8;                 // 392 blocks
    int tid = threadIdx.x;

    __shared__ float xs[128 * 9];
    __shared__ int   cidx[8][4];
    __shared__ float cw[8][4];

    if (tid < 8) {
        int n = n0 + tid;
        float gy = rwo[2 * n], gx = rwo[2 * n + 1];
        float fx = (gx + 1.f) * 27.5f;
        float fy = (gy + 1.f) * 27.5f;
        float x0f = floorf(fx), y0f = floorf(fy);
        float wx = fx - x0f, wy = fy - y0f;
        int x0 = (int)x0f, y0 = (int)y0f;
#pragma unroll
        for (int k = 0; k < 4; k++) {
            int xi = x0 + (k & 1), yi = y0 + (k >> 1);
            float wgt = ((k & 1) ? wx : 1.f - wx) * ((k >> 1) ? wy : 1.f - wy);
            bool v = (xi >= 0) && (xi < WW) && (yi >= 0) && (yi < HH);
            cidx[tid][k] = min(max(yi, 0), HH - 1) * WW + min(max(xi, 0), WW - 1);
            cw[tid][k] = v ? wgt : 0.f;
        }
    }
    __syncthreads();

    // thread = channel c; sample 8 columns (coalesced over c)
#pragma unroll
    for (int j = 0; j < 8; j++) {
        float s = cw[j][0] * xT[cidx[j][0] * 128 + tid]
                + cw[j][1] * xT[cidx[j][1] * 128 + tid]
                + cw[j][2] * xT[cidx[j][2] * 128 + tid]
                + cw[j][3] * xT[cidx[j][3] * 128 + tid];
        xs[tid * 9 + j] = s;
    }
    __syncthreads();

    float ak[8], av[8];
#pragma unroll
    for (int j = 0; j < 8; j++) { ak[j] = 0.f; av[j] = 0.f; }
    for (int c = 0; c < 128; c++) {
        float wk = kwT[c * 128 + tid];
        float wv = vwT[c * 128 + tid];
#pragma unroll
        for (int j = 0; j < 8; j++) {
            float xv = xs[c * 9 + j];
            ak[j] += wk * xv;
            av[j] += wv * xv;
        }
    }
    float kbv = kb[tid], vbv = vb[tid];
    int hh = tid >> 5, ch = tid & 31;
#pragma unroll
    for (int j = 0; j < 8; j++) {
        int addr = (hh * HW + n0 + j) * 32 + ch;
        kT[addr] = ak[j] + kbv;
        vT[addr] = av[j] + vbv;
    }
}

// ---------------- flash attention partials (no LDS; k/v via SGPR broadcast) --------
__global__ __launch_bounds__(256) void attn_partial_kernel(
    const float* __restrict__ query, const float* __restrict__ kT, const float* __restrict__ vT,
    const float* __restrict__ rwo, const float* __restrict__ rpe, float* __restrict__ part,
    int nchunk) {
    const int chunk = blockIdx.x;
    const int mt = blockIdx.y;       // 0..12
    const int hd = blockIdx.z;       // 0..3
    const int tid = threadIdx.x;
    const int m = mt * 256 + tid;
    const int mm = (m < HW) ? m : 0;

    const int nbase = HW / nchunk, nrem = HW % nchunk;
    const int start = chunk * nbase + (chunk < nrem ? chunk : nrem);
    const int len = nbase + (chunk < nrem ? 1 : 0);

    float q[32];
#pragma unroll
    for (int c = 0; c < 32; c++) q[c] = query[(hd * 32 + c) * HW + mm] * SCALE;

    const float fyb = 27.5f * ((float)(mm / WW) * (2.f / 55.f) - 1.f) + 55.f;
    const float fxb = 27.5f * ((float)(mm % WW) * (2.f / 55.f) - 1.f) + 55.f;
    const float* __restrict__ rpeh = rpe + hd * RP * RP;

    const float* __restrict__ kg = kT + (size_t)(hd * HW + start) * 32;
    const float* __restrict__ vg = vT + (size_t)(hd * HW + start) * 32;
    const float* __restrict__ rw = rwo + (size_t)start * 2;

    float maxv = -1e30f, ssum = 0.f;
    float acc[32];
#pragma unroll
    for (int c = 0; c < 32; c++) acc[c] = 0.f;

    for (int j = 0; j < len; j++) {
        // wave-uniform addresses -> s_load, broadcast via SGPR file (no LDS, no VMEM BW)
        const float4* __restrict__ k4 = (const float4*)(kg + (size_t)j * 32);
        const float4* __restrict__ v4 = (const float4*)(vg + (size_t)j * 32);
        float yn = rw[2 * j], xn = rw[2 * j + 1];

        float4 kk[8];
#pragma unroll
        for (int i = 0; i < 8; i++) kk[i] = k4[i];

        float d0 = 0.f, d1 = 0.f, d2 = 0.f, d3 = 0.f;
#pragma unroll
        for (int i = 0; i < 8; i += 4) {
            d0 += q[4*i+ 0]*kk[i  ].x + q[4*i+ 1]*kk[i  ].y + q[4*i+ 2]*kk[i  ].z + q[4*i+ 3]*kk[i  ].w;
            d1 += q[4*i+ 4]*kk[i+1].x + q[4*i+ 5]*kk[i+1].y + q[4*i+ 6]*kk[i+1].z + q[4*i+ 7]*kk[i+1].w;
            d2 += q[4*i+ 8]*kk[i+2].x + q[4*i+ 9]*kk[i+2].y + q[4*i+10]*kk[i+2].z + q[4*i+11]*kk[i+2].w;
            d3 += q[4*i+12]*kk[i+3].x + q[4*i+13]*kk[i+3].y + q[4*i+14]*kk[i+3].z + q[4*i+15]*kk[i+3].w;
        }
        float dot = (d0 + d1) + (d2 + d3);

        // rpe bilinear bias
        float fx = fxb - 27.5f * xn;
        float fy = fyb - 27.5f * yn;
        float x0f = floorf(fx), y0f = floorf(fy);
        float wx = fx - x0f, wy = fy - y0f;
        int x0 = (int)x0f, y0 = (int)y0f;
        int x1 = x0 + 1, y1 = y0 + 1;
        bool vx0 = (unsigned)x0 < (unsigned)RP, vx1 = (unsigned)x1 < (unsigned)RP;
        bool vy0 = (unsigned)y0 < (unsigned)RP, vy1 = (unsigned)y1 < (unsigned)RP;
        int cx0 = min(max(x0, 0), RP - 1), cx1 = min(max(x1, 0), RP - 1);
        int cy0 = min(max(y0, 0), RP - 1), cy1 = min(max(y1, 0), RP - 1);
        float w00 = (1.f - wx) * (1.f - wy) * ((vx0 && vy0) ? 1.f : 0.f);
        float w10 = wx * (1.f - wy) * ((vx1 && vy0) ? 1.f : 0.f);
        float w01 = (1.f - wx) * wy * ((vx0 && vy1) ? 1.f : 0.f);
        float w11 = wx * wy * ((vx1 && vy1) ? 1.f : 0.f);
        float bias = w00 * rpeh[cy0 * RP + cx0] + w10 * rpeh[cy0 * RP + cx1]
                   + w01 * rpeh[cy1 * RP + cx0] + w11 * rpeh[cy1 * RP + cx1];

        float logit = dot + bias;
        if (__builtin_expect(logit > maxv + 8.f, 0)) {   // defer-max: ~only iter 0
            float corr = __expf(maxv - logit);
            ssum *= corr;
#pragma unroll
            for (int c = 0; c < 32; c++) acc[c] *= corr;
            maxv = logit;
        }
        float pr = __expf(logit - maxv);
        ssum += pr;

        float4 vv[8];
#pragma unroll
        for (int i = 0; i < 8; i++) vv[i] = v4[i];
#pragma unroll
        for (int i = 0; i < 8; i++) {
            acc[4*i+0] += pr * vv[i].x;
            acc[4*i+1] += pr * vv[i].y;
            acc[4*i+2] += pr * vv[i].z;
            acc[4*i+3] += pr * vv[i].w;
        }
    }

    if (m < HW) {
        // field-major partials: part[(chunk*34 + f)*GHW + g] — fully coalesced
        float* pb = part + (size_t)(chunk * 34) * GHW + (hd * HW + m);
        pb[0] = maxv;
        pb[GHW] = ssum;
#pragma unroll
        for (int c = 0; c < 32; c++) pb[(size_t)(2 + c) * GHW] = acc[c];
    }
}

// ---------------- combine partials -> att (128 x 3136) ----------------
__global__ __launch_bounds__(256) void combine_kernel(const float* __restrict__ part,
                                                      float* __restrict__ att, int nchunk) {
    int g = blockIdx.x * 256 + threadIdx.x;    // 49 blocks * 256 = 12544 = GHW
    int c0 = blockIdx.y * 8;                   // 4 channel-groups
    int hd = g / HW, m = g % HW;
    const float* pb = part + g;

    float M = -1e30f;
    for (int k = 0; k < nchunk; k++) M = fmaxf(M, pb[(size_t)(k * 34) * GHW]);
    float tot = 0.f;
    float a[8];
#pragma unroll
    for (int cc = 0; cc < 8; cc++) a[cc] = 0.f;
    for (int k = 0; k < nchunk; k++) {
        float e = __expf(pb[(size_t)(k * 34) * GHW] - M);
        tot += pb[(size_t)(k * 34 + 1) * GHW] * e;
#pragma unroll
        for (int cc = 0; cc < 8; cc++)
            a[cc] += pb[(size_t)(k * 34 + 2 + c0 + cc) * GHW] * e;
    }
    float inv = 1.f / tot;
#pragma unroll
    for (int cc = 0; cc < 8; cc++)
        att[(hd * 32 + c0 + cc) * HW + m] = a[cc] * inv;
}

// ---------------- output 1x1 conv (8 cols / block) ----------------
__global__ __launch_bounds__(128) void out_conv_kernel(const float* __restrict__ att,
                                                       const float* __restrict__ owT,
                                                       const float* __restrict__ ob,
                                                       float* __restrict__ out) {
    int m0 = blockIdx.x * 8;                   // 392 blocks
    int tid = threadIdx.x;
    __shared__ float at[128 * 9];
    for (int e = tid; e < 1024; e += 128) {
        int c = e >> 3, j = e & 7;
        at[c * 9 + j] = att[c * HW + m0 + j];
    }
    __syncthreads();

    float a[8];
#pragma unroll
    for (int j = 0; j < 8; j++) a[j] = 0.f;
    for (int c = 0; c < 128; c++) {
        float w = owT[c * 128 + tid];
#pragma unroll
        for (int j = 0; j < 8; j++) a[j] += w * at[c * 9 + j];
    }
    float b = ob[tid];
#pragma unroll
    for (int j = 0; j < 8; j++) out[tid * HW + m0 + j] = a[j] + b;
}

extern "C" void kernel_launch(void* const* d_in, const int* in_sizes, int n_in,
                              void* d_out, int out_size, void* d_ws, size_t ws_size,
                              hipStream_t stream) {
    const float* x     = (const float*)d_in[0];
    const float* query = (const float*)d_in[1];
    const float* dww   = (const float*)d_in[2];
    const float* dwb   = (const float*)d_in[3];
    const float* lnw   = (const float*)d_in[4];
    const float* lnb   = (const float*)d_in[5];
    const float* pww   = (const float*)d_in[6];
    const float* kw    = (const float*)d_in[7];
    const float* kb    = (const float*)d_in[8];
    const float* vw    = (const float*)d_in[9];
    const float* vb    = (const float*)d_in[10];
    const float* ow    = (const float*)d_in[11];
    const float* ob    = (const float*)d_in[12];
    const float* rpe   = (const float*)d_in[13];
    float* out = (float*)d_out;
    float* ws  = (float*)d_ws;

    // pick chunk count from available workspace (deterministic across calls)
    long ws_floats = (long)(ws_size / 4);
    long avail = ws_floats - (long)OFF_PART;
    int nchunk = (int)(avail / ((long)34 * GHW));
    if (nchunk > 28) nchunk = 28;
    if (nchunk < 2) nchunk = 2;

    tw_kernel<<<dim3(64, 3), 256, 0, stream>>>(kw, vw, ow,
                                               ws + OFF_KWT, ws + OFF_VWT, ws + OFF_OWT);
    tx_kernel<<<dim3(98, 4, 2), 256, 0, stream>>>(x, query, ws + OFF_XT, ws + OFF_QT);
    offset_kernel<<<HW, 128, 0, stream>>>(ws + OFF_QT, dww, dwb, lnw, lnb, pww, ws + OFF_RWO);
    sample_kv_kernel<<<392, 128, 0, stream>>>(ws + OFF_XT, ws + OFF_RWO,
                                              ws + OFF_KWT, ws + OFF_VWT, kb, vb,
                                              ws + OFF_KT, ws + OFF_VT);
    attn_partial_kernel<<<dim3(nchunk, 13, NHEAD), 256, 0, stream>>>(
        query, ws + OFF_KT, ws + OFF_VT, ws + OFF_RWO, rpe, ws + OFF_PART, nchunk);
    combine_kernel<<<dim3(49, 4), 256, 0, stream>>>(ws + OFF_PART, ws + OFF_ATT, nchunk);
    out_conv_kernel<<<392, 128, 0, stream>>>(ws + OFF_ATT, ws + OFF_OWT, ob, out);
}

// Round 3
// 231.201 us; speedup vs baseline: 2.5927x; 1.3637x over previous
//
#include <hip/hip_runtime.h>
#include <hip/hip_bf16.h>
#include <math.h>

#define HH 56
#define WW 56
#define HW 3136
#define NHEAD 4
#define RP 111
#define TP 113                       // padded rpe table dim
#define TPE 12769                    // 113*113
#define SCALE 0.17677669529663687f   // 32^-0.5
#define GHW 12544                    // NHEAD*HW

// ---- ws layout (float offsets) ----
#define OFF_RWO  0u                          // 3136*2, pad 8192
#define OFF_AA   8192u                       // 3136 ints, pad 4096
#define OFF_W4   12288u                      // 3136 float4 = 12544
#define OFF_KT   24832u                      // 4*3136*32, layout (h, n, c)
#define OFF_VT   (OFF_KT + 401408u)
#define OFF_ATT  (OFF_VT + 401408u)          // 128 x 3136
#define OFF_KWT  (OFF_ATT + 401408u)         // 128x128 transposed
#define OFF_VWT  (OFF_KWT + 16384u)
#define OFF_OWT  (OFF_VWT + 16384u)
#define OFF_XT   (OFF_OWT + 16384u)          // 3136 x 128  (p, c)
#define OFF_QT   (OFF_XT + 401408u)          // 3136 x 128  (p, c)
#define OFF_TPAD (OFF_QT + 401408u)          // 4*113*113 = 51076, pad 51200
#define OFF_PART (OFF_TPAD + 51200u)         // nchunk * 33 * GHW, field-major

// ---------------- prep: transpose 3 weights + build zero-padded rpe table -------
__global__ void prep_kernel(const float* __restrict__ a, const float* __restrict__ b,
                            const float* __restrict__ c, const float* __restrict__ rpe,
                            float* __restrict__ at, float* __restrict__ bt,
                            float* __restrict__ ct, float* __restrict__ tpad) {
    int i = blockIdx.x * 256 + threadIdx.x;
    if (blockIdx.y < 3) {
        if (i >= 16384) return;
        const float* src = (blockIdx.y == 0) ? a : (blockIdx.y == 1) ? b : c;
        float* dst       = (blockIdx.y == 0) ? at : (blockIdx.y == 1) ? bt : ct;
        int o = i >> 7, cc = i & 127;
        dst[cc * 128 + o] = src[i];
    } else {
        if (i >= NHEAD * TPE) return;
        int hd = i / TPE, r = i % TPE;
        int py = r / TP, px = r % TP;
        float v = 0.f;
        if (py >= 1 && py <= RP && px >= 1 && px <= RP)
            v = rpe[hd * RP * RP + (py - 1) * RP + (px - 1)];
        tpad[i] = v;
    }
}

// ---------------- tiled transpose (c, p) -> (p, c) for x and query ----------------
__global__ __launch_bounds__(256) void tx_kernel(const float* __restrict__ x,
                                                 const float* __restrict__ query,
                                                 float* __restrict__ xT, float* __restrict__ qT) {
    const float* src = blockIdx.z ? query : x;
    float* dst       = blockIdx.z ? qT : xT;
    __shared__ float tile[32][33];
    int pt = blockIdx.x * 32;     // 98 tiles
    int ct = blockIdx.y * 32;     // 4 tiles
    int jj = threadIdx.x & 31, ii = threadIdx.x >> 5;
#pragma unroll
    for (int r = 0; r < 4; r++)
        tile[ii + r * 8][jj] = src[(ct + ii + r * 8) * HW + pt + jj];
    __syncthreads();
#pragma unroll
    for (int r = 0; r < 4; r++)
        dst[(pt + ii + r * 8) * 128 + ct + jj] = tile[jj][ii + r * 8];
}

__device__ __forceinline__ float wave_sum(float v) {
#pragma unroll
    for (int o = 1; o < 64; o <<= 1) v += __shfl_xor(v, o);
    return v;
}

// ------- offset field: dwconv3x3 + LN + GELU + 1x1 -> rwo + per-n bias prep -------
__global__ __launch_bounds__(128) void offset_kernel(
    const float* __restrict__ qT, const float* __restrict__ dww, const float* __restrict__ dwb,
    const float* __restrict__ lnw, const float* __restrict__ lnb, const float* __restrict__ pww,
    float* __restrict__ rwo, int* __restrict__ aa, float* __restrict__ w4) {
    int p = blockIdx.x;
    int c = threadIdx.x;
    int h = p / WW, w = p % WW;

    float t = dwb[c];
#pragma unroll
    for (int ky = 0; ky < 3; ky++) {
        int yy = h + ky - 1;
        if ((unsigned)yy < (unsigned)HH) {
#pragma unroll
            for (int kx = 0; kx < 3; kx++) {
                int xx = w + kx - 1;
                if ((unsigned)xx < (unsigned)WW)
                    t += qT[(yy * WW + xx) * 128 + c] * dww[c * 9 + ky * 3 + kx];
            }
        }
    }

    __shared__ float sred[4];
    int wid = c >> 6, lane0 = ((c & 63) == 0);

    float s = wave_sum(t);
    if (lane0) sred[wid] = s;
    __syncthreads();
    float mu = (sred[0] + sred[1]) * (1.f / 128.f);
    float d = t - mu;
    __syncthreads();
    s = wave_sum(d * d);
    if (lane0) sred[wid] = s;
    __syncthreads();
    float var = (sred[0] + sred[1]) * (1.f / 128.f);

    float tn = d / sqrtf(var + 1e-5f) * lnw[c] + lnb[c];
    float g = 0.5f * tn * (1.f + erff(tn * 0.70710678118654752f));

    float sy = wave_sum(g * pww[c]);
    float sx = wave_sum(g * pww[128 + c]);
    __syncthreads();
    if (lane0) { sred[wid] = sy; sred[2 + wid] = sx; }
    __syncthreads();
    if (c == 0) {
        float thy = tanhf(sred[0] + sred[1]);
        float thx = tanhf(sred[2] + sred[3]);
        rwo[p * 2]     = thy * (0.5f / 55.f) + ((float)h * (2.f / 55.f) - 1.f);
        rwo[p * 2 + 1] = thx * (0.5f / 55.f) + ((float)w * (2.f / 55.f) - 1.f);
        // bias prep: fx(m,n) = col_m + tx_n, fy(m,n) = row_m + ty_n
        float ty = 55.f - (float)h - 0.25f * thy;
        float tx = 55.f - (float)w - 0.25f * thx;
        float tyf = floorf(ty), txf = floorf(tx);
        float wy = ty - tyf, wx = tx - txf;
        aa[p] = ((int)tyf) * TP + (int)txf + TP + 1;   // into padded table
        float4 wv;
        wv.x = (1.f - wx) * (1.f - wy);
        wv.y = wx * (1.f - wy);
        wv.z = (1.f - wx) * wy;
        wv.w = wx * wy;
        ((float4*)w4)[p] = wv;
    }
}

// ---------------- bilinear sample + k/v projection (8 cols / block) ----------------
__global__ __launch_bounds__(128) void sample_kv_kernel(
    const float* __restrict__ xT, const float* __restrict__ rwo,
    const float* __restrict__ kwT, const float* __restrict__ vwT,
    const float* __restrict__ kb, const float* __restrict__ vb,
    float* __restrict__ kT, float* __restrict__ vT) {
    int n0 = blockIdx.x * 8;                 // 392 blocks
    int tid = threadIdx.x;

    __shared__ float xs[128 * 9];
    __shared__ int   cidx[8][4];
    __shared__ float cw[8][4];

    if (tid < 8) {
        int n = n0 + tid;
        float gy = rwo[2 * n], gx = rwo[2 * n + 1];
        float fx = (gx + 1.f) * 27.5f;
        float fy = (gy + 1.f) * 27.5f;
        float x0f = floorf(fx), y0f = floorf(fy);
        float wx = fx - x0f, wy = fy - y0f;
        int x0 = (int)x0f, y0 = (int)y0f;
#pragma unroll
        for (int k = 0; k < 4; k++) {
            int xi = x0 + (k & 1), yi = y0 + (k >> 1);
            float wgt = ((k & 1) ? wx : 1.f - wx) * ((k >> 1) ? wy : 1.f - wy);
            bool v = (xi >= 0) && (xi < WW) && (yi >= 0) && (yi < HH);
            cidx[tid][k] = min(max(yi, 0), HH - 1) * WW + min(max(xi, 0), WW - 1);
            cw[tid][k] = v ? wgt : 0.f;
        }
    }
    __syncthreads();

#pragma unroll
    for (int j = 0; j < 8; j++) {
        float s = cw[j][0] * xT[cidx[j][0] * 128 + tid]
                + cw[j][1] * xT[cidx[j][1] * 128 + tid]
                + cw[j][2] * xT[cidx[j][2] * 128 + tid]
                + cw[j][3] * xT[cidx[j][3] * 128 + tid];
        xs[tid * 9 + j] = s;
    }
    __syncthreads();

    float ak[8], av[8];
#pragma unroll
    for (int j = 0; j < 8; j++) { ak[j] = 0.f; av[j] = 0.f; }
    for (int c = 0; c < 128; c++) {
        float wk = kwT[c * 128 + tid];
        float wv = vwT[c * 128 + tid];
#pragma unroll
        for (int j = 0; j < 8; j++) {
            float xv = xs[c * 9 + j];
            ak[j] += wk * xv;
            av[j] += wv * xv;
        }
    }
    float kbv = kb[tid], vbv = vb[tid];
    int hh = tid >> 5, ch = tid & 31;
#pragma unroll
    for (int j = 0; j < 8; j++) {
        int addr = (hh * HW + n0 + j) * 32 + ch;
        kT[addr] = ak[j] + kbv;
        vT[addr] = av[j] + vbv;
    }
}

// -------- attention partials: no online max (logits are O(1)), prepped bias -------
__global__ __launch_bounds__(256) void attn_partial_kernel(
    const float* __restrict__ query, const float* __restrict__ kT, const float* __restrict__ vT,
    const int* __restrict__ aa, const float* __restrict__ w4, const float* __restrict__ tpad,
    float* __restrict__ part, int nchunk) {
    const int chunk = blockIdx.x;
    const int mt = blockIdx.y;       // 0..12
    const int hd = blockIdx.z;       // 0..3
    const int tid = threadIdx.x;
    const int m = mt * 256 + tid;
    const int mm = (m < HW) ? m : 0;

    const int nbase = HW / nchunk, nrem = HW % nchunk;
    const int start = chunk * nbase + (chunk < nrem ? chunk : nrem);
    const int len = nbase + (chunk < nrem ? 1 : 0);

    float q[32];
#pragma unroll
    for (int c = 0; c < 32; c++) q[c] = query[(hd * 32 + c) * HW + mm] * SCALE;

    const int base_m = (mm / WW) * TP + (mm % WW);
    const float* __restrict__ tp = tpad + hd * TPE;

    const float* __restrict__ kg = kT + (size_t)(hd * HW + start) * 32;
    const float* __restrict__ vg = vT + (size_t)(hd * HW + start) * 32;
    const int* __restrict__ aan = aa + start;
    const float4* __restrict__ w4n = ((const float4*)w4) + start;

    float ssum = 0.f;
    float acc[32];
#pragma unroll
    for (int c = 0; c < 32; c++) acc[c] = 0.f;

    for (int j = 0; j < len; j++) {
        // wave-uniform -> s_load broadcast (no LDS, no per-lane VMEM for k/v)
        const float4* __restrict__ k4 = (const float4*)(kg + (size_t)j * 32);
        const float4* __restrict__ v4 = (const float4*)(vg + (size_t)j * 32);
        const float4 wv = w4n[j];
        const int a0 = aan[j] + base_m;

        float4 kk[8];
#pragma unroll
        for (int i = 0; i < 8; i++) kk[i] = k4[i];

        float d0 = 0.f, d1 = 0.f, d2 = 0.f, d3 = 0.f;
#pragma unroll
        for (int i = 0; i < 8; i += 4) {
            d0 += q[4*i+ 0]*kk[i  ].x + q[4*i+ 1]*kk[i  ].y + q[4*i+ 2]*kk[i  ].z + q[4*i+ 3]*kk[i  ].w;
            d1 += q[4*i+ 4]*kk[i+1].x + q[4*i+ 5]*kk[i+1].y + q[4*i+ 6]*kk[i+1].z + q[4*i+ 7]*kk[i+1].w;
            d2 += q[4*i+ 8]*kk[i+2].x + q[4*i+ 9]*kk[i+2].y + q[4*i+10]*kk[i+2].z + q[4*i+11]*kk[i+2].w;
            d3 += q[4*i+12]*kk[i+3].x + q[4*i+13]*kk[i+3].y + q[4*i+14]*kk[i+3].z + q[4*i+15]*kk[i+3].w;
        }

        float bias = wv.x * tp[a0]      + wv.y * tp[a0 + 1]
                   + wv.z * tp[a0 + TP] + wv.w * tp[a0 + TP + 1];

        float pr = __expf(((d0 + d1) + (d2 + d3)) + bias);
        ssum += pr;

        float4 vv[8];
#pragma unroll
        for (int i = 0; i < 8; i++) vv[i] = v4[i];
#pragma unroll
        for (int i = 0; i < 8; i++) {
            acc[4*i+0] += pr * vv[i].x;
            acc[4*i+1] += pr * vv[i].y;
            acc[4*i+2] += pr * vv[i].z;
            acc[4*i+3] += pr * vv[i].w;
        }
    }

    if (m < HW) {
        // field-major partials: part[(chunk*33 + f)*GHW + g]
        float* pb = part + (size_t)(chunk * 33) * GHW + (hd * HW + m);
        pb[0] = ssum;
#pragma unroll
        for (int c = 0; c < 32; c++) pb[(size_t)(1 + c) * GHW] = acc[c];
    }
}

// ---------------- combine partials -> att (128 x 3136) ----------------
__global__ __launch_bounds__(256) void combine_kernel(const float* __restrict__ part,
                                                      float* __restrict__ att, int nchunk) {
    int g = blockIdx.x * 256 + threadIdx.x;    // 49*256 = GHW
    int c0 = blockIdx.y * 8;
    int hd = g / HW, m = g % HW;
    const float* pb = part + g;

    float s = 0.f;
    float a[8];
#pragma unroll
    for (int cc = 0; cc < 8; cc++) a[cc] = 0.f;
    for (int k = 0; k < nchunk; k++) {
        s += pb[(size_t)(k * 33) * GHW];
#pragma unroll
        for (int cc = 0; cc < 8; cc++)
            a[cc] += pb[(size_t)(k * 33 + 1 + c0 + cc) * GHW];
    }
    float inv = 1.f / s;
#pragma unroll
    for (int cc = 0; cc < 8; cc++)
        att[(hd * 32 + c0 + cc) * HW + m] = a[cc] * inv;
}

// ---------------- output 1x1 conv (8 cols / block) ----------------
__global__ __launch_bounds__(128) void out_conv_kernel(const float* __restrict__ att,
                                                       const float* __restrict__ owT,
                                                       const float* __restrict__ ob,
                                                       float* __restrict__ out) {
    int m0 = blockIdx.x * 8;                   // 392 blocks
    int tid = threadIdx.x;
    __shared__ float at[128 * 9];
    for (int e = tid; e < 1024; e += 128) {
        int c = e >> 3, j = e & 7;
        at[c * 9 + j] = att[c * HW + m0 + j];
    }
    __syncthreads();

    float a[8];
#pragma unroll
    for (int j = 0; j < 8; j++) a[j] = 0.f;
    for (int c = 0; c < 128; c++) {
        float w = owT[c * 128 + tid];
#pragma unroll
        for (int j = 0; j < 8; j++) a[j] += w * at[c * 9 + j];
    }
    float b = ob[tid];
#pragma unroll
    for (int j = 0; j < 8; j++) out[tid * HW + m0 + j] = a[j] + b;
}

extern "C" void kernel_launch(void* const* d_in, const int* in_sizes, int n_in,
                              void* d_out, int out_size, void* d_ws, size_t ws_size,
                              hipStream_t stream) {
    const float* x     = (const float*)d_in[0];
    const float* query = (const float*)d_in[1];
    const float* dww   = (const float*)d_in[2];
    const float* dwb   = (const float*)d_in[3];
    const float* lnw   = (const float*)d_in[4];
    const float* lnb   = (const float*)d_in[5];
    const float* pww   = (const float*)d_in[6];
    const float* kw    = (const float*)d_in[7];
    const float* kb    = (const float*)d_in[8];
    const float* vw    = (const float*)d_in[9];
    const float* vb    = (const float*)d_in[10];
    const float* ow    = (const float*)d_in[11];
    const float* ob    = (const float*)d_in[12];
    const float* rpe   = (const float*)d_in[13];
    float* out = (float*)d_out;
    float* ws  = (float*)d_ws;

    long ws_floats = (long)(ws_size / 4);
    long avail = ws_floats - (long)OFF_PART;
    int nchunk = (int)(avail / ((long)33 * GHW));
    if (nchunk > 28) nchunk = 28;
    if (nchunk < 2) nchunk = 2;

    prep_kernel<<<dim3(200, 4), 256, 0, stream>>>(kw, vw, ow, rpe,
                                                  ws + OFF_KWT, ws + OFF_VWT, ws + OFF_OWT,
                                                  ws + OFF_TPAD);
    tx_kernel<<<dim3(98, 4, 2), 256, 0, stream>>>(x, query, ws + OFF_XT, ws + OFF_QT);
    offset_kernel<<<HW, 128, 0, stream>>>(ws + OFF_QT, dww, dwb, lnw, lnb, pww,
                                          ws + OFF_RWO, (int*)(ws + OFF_AA), ws + OFF_W4);
    sample_kv_kernel<<<392, 128, 0, stream>>>(ws + OFF_XT, ws + OFF_RWO,
                                              ws + OFF_KWT, ws + OFF_VWT, kb, vb,
                                              ws + OFF_KT, ws + OFF_VT);
    attn_partial_kernel<<<dim3(nchunk, 13, NHEAD), 256, 0, stream>>>(
        query, ws + OFF_KT, ws + OFF_VT,
        (const int*)(ws + OFF_AA), ws + OFF_W4, ws + OFF_TPAD, ws + OFF_PART, nchunk);
    combine_kernel<<<dim3(49, 4), 256, 0, stream>>>(ws + OFF_PART, ws + OFF_ATT, nchunk);
    out_conv_kernel<<<392, 128, 0, stream>>>(ws + OFF_ATT, ws + OFF_OWT, ob, out);
}

// Round 4
// 195.509 us; speedup vs baseline: 3.0660x; 1.1826x over previous
//
#include <hip/hip_runtime.h>
#include <hip/hip_bf16.h>
#include <math.h>

#define HH 56
#define WW 56
#define HW 3136
#define NHEAD 4
#define RP 111
#define TP 113                       // padded rpe table dim
#define TPE 12769                    // 113*113
#define SCALE 0.17677669529663687f   // 32^-0.5
#define GHW 12544                    // NHEAD*HW
#define NCHUNK 14
#define CLEN 224                     // 3136/14
#define NSTEP 7                      // 224/32

typedef unsigned short ushortT;
typedef __attribute__((ext_vector_type(8))) short short8v;
typedef __attribute__((ext_vector_type(16))) float f32x16;

// ---- ws layout (float offsets) ----
#define OFF_RWO  0u
#define OFF_AA   8192u
#define OFF_W4   12288u
#define OFF_KBF  24832u                      // 4*3136*32 ushort = 200704 floats
#define OFF_VBF  225536u                     // (h,c,n) bf16
#define OFF_QBF  426240u                     // (h,m,c) bf16, SCALE folded
#define OFF_ATT  626944u                     // 128 x 3136 f32
#define OFF_KWT  1028352u
#define OFF_VWT  1044736u
#define OFF_OWT  1061120u
#define OFF_XT   1077504u                    // 3136 x 128 f32
#define OFF_QT   1478912u                    // 3136 x 128 f32
#define OFF_TP2  1880320u                    // 4*113*113 float2 = 102152 floats
#define OFF_PART 1982976u                    // NCHUNK*33*GHW

__device__ __forceinline__ ushortT f2bf(float f) {
    unsigned u = __float_as_uint(f);
    u += 0x7fffu + ((u >> 16) & 1u);
    return (ushortT)(u >> 16);
}

__device__ __forceinline__ unsigned cvtpk(float lo, float hi) {
    unsigned r;
    asm("v_cvt_pk_bf16_f32 %0, %1, %2" : "=v"(r) : "v"(lo), "v"(hi));
    return r;
}

// ---------------- prep: transpose 3 weights + build padded float2 rpe table ------
__global__ void prep_kernel(const float* __restrict__ a, const float* __restrict__ b,
                            const float* __restrict__ c, const float* __restrict__ rpe,
                            float* __restrict__ at, float* __restrict__ bt,
                            float* __restrict__ ct, float2* __restrict__ tp2) {
    int i = blockIdx.x * 256 + threadIdx.x;
    if (blockIdx.y < 3) {
        if (i >= 16384) return;
        const float* src = (blockIdx.y == 0) ? a : (blockIdx.y == 1) ? b : c;
        float* dst       = (blockIdx.y == 0) ? at : (blockIdx.y == 1) ? bt : ct;
        int o = i >> 7, cc = i & 127;
        dst[cc * 128 + o] = src[i];
    } else {
        if (i >= NHEAD * TPE) return;
        int hd = i / TPE, r = i % TPE;
        int py = r / TP, px = r % TP;
        float v0 = 0.f, v1 = 0.f;
        if (py >= 1 && py <= RP) {
            if (px >= 1 && px <= RP)     v0 = rpe[hd * RP * RP + (py - 1) * RP + (px - 1)];
            if (px + 1 >= 1 && px + 1 <= RP) v1 = rpe[hd * RP * RP + (py - 1) * RP + px];
        }
        tp2[i] = make_float2(v0, v1);
    }
}

// ------- tiled transpose (c,p)->(p,c) for x and query; also emit qbf bf16 --------
__global__ __launch_bounds__(256) void tx_kernel(const float* __restrict__ x,
                                                 const float* __restrict__ query,
                                                 float* __restrict__ xT, float* __restrict__ qT,
                                                 ushortT* __restrict__ qbf) {
    const float* src = blockIdx.z ? query : x;
    float* dst       = blockIdx.z ? qT : xT;
    __shared__ float tile[32][33];
    int pt = blockIdx.x * 32;
    int ct = blockIdx.y * 32;
    int jj = threadIdx.x & 31, ii = threadIdx.x >> 5;
#pragma unroll
    for (int r = 0; r < 4; r++)
        tile[ii + r * 8][jj] = src[(ct + ii + r * 8) * HW + pt + jj];
    __syncthreads();
#pragma unroll
    for (int r = 0; r < 4; r++) {
        int p = pt + ii + r * 8, c = ct + jj;
        float val = tile[jj][ii + r * 8];
        dst[p * 128 + c] = val;
        if (blockIdx.z)
            qbf[(size_t)((c >> 5) * HW + p) * 32 + (c & 31)] = f2bf(val * SCALE);
    }
}

__device__ __forceinline__ float wave_sum(float v) {
#pragma unroll
    for (int o = 1; o < 64; o <<= 1) v += __shfl_xor(v, o);
    return v;
}

// ------- offset field: dwconv3x3 + LN + GELU + 1x1 -> rwo + per-n bias prep -------
__global__ __launch_bounds__(128) void offset_kernel(
    const float* __restrict__ qT, const float* __restrict__ dww, const float* __restrict__ dwb,
    const float* __restrict__ lnw, const float* __restrict__ lnb, const float* __restrict__ pww,
    float* __restrict__ rwo, int* __restrict__ aa, float* __restrict__ w4) {
    int p = blockIdx.x;
    int c = threadIdx.x;
    int h = p / WW, w = p % WW;

    float t = dwb[c];
#pragma unroll
    for (int ky = 0; ky < 3; ky++) {
        int yy = h + ky - 1;
        if ((unsigned)yy < (unsigned)HH) {
#pragma unroll
            for (int kx = 0; kx < 3; kx++) {
                int xx = w + kx - 1;
                if ((unsigned)xx < (unsigned)WW)
                    t += qT[(yy * WW + xx) * 128 + c] * dww[c * 9 + ky * 3 + kx];
            }
        }
    }

    __shared__ float sred[4];
    int wid = c >> 6, lane0 = ((c & 63) == 0);

    float s = wave_sum(t);
    if (lane0) sred[wid] = s;
    __syncthreads();
    float mu = (sred[0] + sred[1]) * (1.f / 128.f);
    float d = t - mu;
    __syncthreads();
    s = wave_sum(d * d);
    if (lane0) sred[wid] = s;
    __syncthreads();
    float var = (sred[0] + sred[1]) * (1.f / 128.f);

    float tn = d / sqrtf(var + 1e-5f) * lnw[c] + lnb[c];
    float g = 0.5f * tn * (1.f + erff(tn * 0.70710678118654752f));

    float sy = wave_sum(g * pww[c]);
    float sx = wave_sum(g * pww[128 + c]);
    __syncthreads();
    if (lane0) { sred[wid] = sy; sred[2 + wid] = sx; }
    __syncthreads();
    if (c == 0) {
        float thy = tanhf(sred[0] + sred[1]);
        float thx = tanhf(sred[2] + sred[3]);
        rwo[p * 2]     = thy * (0.5f / 55.f) + ((float)h * (2.f / 55.f) - 1.f);
        rwo[p * 2 + 1] = thx * (0.5f / 55.f) + ((float)w * (2.f / 55.f) - 1.f);
        float ty = 55.f - (float)h - 0.25f * thy;
        float tx = 55.f - (float)w - 0.25f * thx;
        float tyf = floorf(ty), txf = floorf(tx);
        float wy = ty - tyf, wx = tx - txf;
        aa[p] = ((int)tyf) * TP + (int)txf + TP + 1;
        float4 wv;
        wv.x = (1.f - wx) * (1.f - wy);
        wv.y = wx * (1.f - wy);
        wv.z = (1.f - wx) * wy;
        wv.w = wx * wy;
        ((float4*)w4)[p] = wv;
    }
}

// ------- bilinear sample + k/v projection -> bf16 K (h,n,c) and V (h,c,n) --------
__global__ __launch_bounds__(128) void sample_kv_kernel(
    const float* __restrict__ xT, const float* __restrict__ rwo,
    const float* __restrict__ kwT, const float* __restrict__ vwT,
    const float* __restrict__ kb, const float* __restrict__ vb,
    ushortT* __restrict__ kbf, ushortT* __restrict__ vbf) {
    int n0 = blockIdx.x * 8;                 // 392 blocks
    int tid = threadIdx.x;

    __shared__ float xs[128 * 9];
    __shared__ int   cidx[8][4];
    __shared__ float cw[8][4];
    __shared__ ushortT kst[8][128];

    if (tid < 8) {
        int n = n0 + tid;
        float gy = rwo[2 * n], gx = rwo[2 * n + 1];
        float fx = (gx + 1.f) * 27.5f;
        float fy = (gy + 1.f) * 27.5f;
        float x0f = floorf(fx), y0f = floorf(fy);
        float wx = fx - x0f, wy = fy - y0f;
        int x0 = (int)x0f, y0 = (int)y0f;
#pragma unroll
        for (int k = 0; k < 4; k++) {
            int xi = x0 + (k & 1), yi = y0 + (k >> 1);
            float wgt = ((k & 1) ? wx : 1.f - wx) * ((k >> 1) ? wy : 1.f - wy);
            bool v = (xi >= 0) && (xi < WW) && (yi >= 0) && (yi < HH);
            cidx[tid][k] = min(max(yi, 0), HH - 1) * WW + min(max(xi, 0), WW - 1);
            cw[tid][k] = v ? wgt : 0.f;
        }
    }
    __syncthreads();

#pragma unroll
    for (int j = 0; j < 8; j++) {
        float s = cw[j][0] * xT[cidx[j][0] * 128 + tid]
                + cw[j][1] * xT[cidx[j][1] * 128 + tid]
                + cw[j][2] * xT[cidx[j][2] * 128 + tid]
                + cw[j][3] * xT[cidx[j][3] * 128 + tid];
        xs[tid * 9 + j] = s;
    }
    __syncthreads();

    float ak[8], av[8];
#pragma unroll
    for (int j = 0; j < 8; j++) { ak[j] = 0.f; av[j] = 0.f; }
    for (int c = 0; c < 128; c++) {
        float wk = kwT[c * 128 + tid];
        float wv = vwT[c * 128 + tid];
#pragma unroll
        for (int j = 0; j < 8; j++) {
            float xv = xs[c * 9 + j];
            ak[j] += wk * xv;
            av[j] += wv * xv;
        }
    }
    float kbv = kb[tid], vbv = vb[tid];
    int hh = tid >> 5, ch = tid & 31;

    // V (h, c, n): one 16B store per thread (8 consecutive n)
    unsigned vp[4];
#pragma unroll
    for (int q = 0; q < 4; q++)
        vp[q] = (unsigned)f2bf(av[2 * q] + vbv) | ((unsigned)f2bf(av[2 * q + 1] + vbv) << 16);
    *(uint4*)(vbf + (size_t)(hh * 32 + ch) * HW + n0) = make_uint4(vp[0], vp[1], vp[2], vp[3]);

    // K (h, n, c): stage in LDS then coalesced dword stores
#pragma unroll
    for (int j = 0; j < 8; j++) kst[j][tid] = f2bf(ak[j] + kbv);
    __syncthreads();
#pragma unroll
    for (int r = 0; r < 4; r++) {
        int lin = tid + 128 * r;        // 512 dwords
        int j = lin >> 6, dd = lin & 63;
        int o = 2 * dd;
        unsigned val = *(unsigned*)&kst[j][o];
        int hd2 = o >> 5, ch2 = o & 31;
        ((unsigned*)kbf)[((size_t)(hd2 * HW + n0 + j) * 32 + ch2) >> 1] = val;
    }
}

// -------- MFMA flash attention partials (32x32 tiles, swapped QK^T) --------------
__device__ __forceinline__ void mkw(float pa0, float pa1, float pb0, float pb1, int h,
                                    unsigned &wlo, unsigned &whi) {
    float ta0 = __shfl_xor(pa0, 32);
    float ta1 = __shfl_xor(pa1, 32);
    float tb0 = __shfl_xor(pb0, 32);
    float tb1 = __shfl_xor(pb1, 32);
    wlo = cvtpk(h ? tb0 : pa0, h ? tb1 : pa1);
    whi = cvtpk(h ? pb0 : ta0, h ? pb1 : ta1);
}

__global__ __launch_bounds__(256) void attn_kernel(
    const ushortT* __restrict__ qbf, const ushortT* __restrict__ kbf,
    const ushortT* __restrict__ vbf,
    const int* __restrict__ aa, const float4* __restrict__ w4,
    const float2* __restrict__ tp2g, float* __restrict__ part) {
    const int chunk = blockIdx.x;      // 0..13
    const int mtile = blockIdx.y;      // 0..24
    const int hd = blockIdx.z;         // 0..3
    const int tid = threadIdx.x;
    const int wv = tid >> 6;
    const int l = tid & 63;
    const int lm = l & 31;
    const int h = l >> 5;

    const int start = chunk * CLEN;
    const int m0w = mtile * 128 + wv * 32;
    const int mg = m0w + lm;
    const int mc = (mg < HW) ? mg : (HW - 1);

    __shared__ int aa_s[CLEN];
    __shared__ float4 w4_s[CLEN];
    __shared__ float obuf[4][32][33];

    if (tid < CLEN) { aa_s[tid] = aa[start + tid]; w4_s[tid] = ((const float4*)w4)[start + tid]; }
    __syncthreads();

    const int base_m = (mc / WW) * TP + (mc % WW);
    const float2* __restrict__ tp2 = tp2g + hd * TPE;

    const ushortT* qb = qbf + (size_t)(hd * HW + mc) * 32 + h * 8;
    short8v qf0 = *(const short8v*)(qb);
    short8v qf1 = *(const short8v*)(qb + 16);

    const ushortT* kbp = kbf + (size_t)(hd * HW + start) * 32;
    const ushortT* vbp = vbf + (size_t)(hd * 32 + lm) * HW + start;

    f32x16 accO;
#pragma unroll
    for (int i = 0; i < 16; i++) accO[i] = 0.f;
    float ssum = 0.f;

    for (int nt = 0; nt < NSTEP; ++nt) {
        const ushortT* ka = kbp + (size_t)(nt * 32 + lm) * 32 + h * 8;
        short8v kf0 = *(const short8v*)(ka);
        short8v kf1 = *(const short8v*)(ka + 16);
        f32x16 s;
#pragma unroll
        for (int i = 0; i < 16; i++) s[i] = 0.f;
        s = __builtin_amdgcn_mfma_f32_32x32x16_bf16(kf0, qf0, s, 0, 0, 0);
        s = __builtin_amdgcn_mfma_f32_32x32x16_bf16(kf1, qf1, s, 0, 0, 0);

        float p[16];
#pragma unroll
        for (int r = 0; r < 16; ++r) {
            int nl = nt * 32 + (r & 3) + 8 * (r >> 2) + 4 * h;
            int a0 = aa_s[nl] + base_m;
            float4 wvv = w4_s[nl];
            float2 t01 = tp2[a0];
            float2 t23 = tp2[a0 + TP];
            float bias = wvv.x * t01.x + wvv.y * t01.y + wvv.z * t23.x + wvv.w * t23.y;
            float pr = __expf(s[r] + bias);
            ssum += pr;
            p[r] = pr;
        }

        union { unsigned u[4]; short8v s8; } A0, A1;
        mkw(p[0], p[1], p[4], p[5], h, A0.u[0], A0.u[2]);
        mkw(p[2], p[3], p[6], p[7], h, A0.u[1], A0.u[3]);
        mkw(p[8], p[9], p[12], p[13], h, A1.u[0], A1.u[2]);
        mkw(p[10], p[11], p[14], p[15], h, A1.u[1], A1.u[3]);

        const ushortT* va = vbp + nt * 32 + h * 8;
        short8v vf0 = *(const short8v*)(va);
        short8v vf1 = *(const short8v*)(va + 16);
        accO = __builtin_amdgcn_mfma_f32_32x32x16_bf16(A0.s8, vf0, accO, 0, 0, 0);
        accO = __builtin_amdgcn_mfma_f32_32x32x16_bf16(A1.s8, vf1, accO, 0, 0, 0);
    }

    float st = ssum + __shfl_xor(ssum, 32);

#pragma unroll
    for (int r = 0; r < 16; ++r) {
        int mr = (r & 3) + 8 * (r >> 2) + 4 * h;
        obuf[wv][mr][lm] = accO[r];
    }
    __syncthreads();

    float* pbase = part + (size_t)(chunk * 33) * GHW + hd * HW;
    if (mg < HW) {
        if (h == 0) pbase[mg] = st;
        int c0 = h * 16;
#pragma unroll
        for (int k = 0; k < 4; ++k) {
            float4 o4 = *(const float4*)&obuf[wv][lm][c0 + 4 * k];
            pbase[(size_t)(1 + c0 + 4 * k + 0) * GHW + mg] = o4.x;
            pbase[(size_t)(1 + c0 + 4 * k + 1) * GHW + mg] = o4.y;
            pbase[(size_t)(1 + c0 + 4 * k + 2) * GHW + mg] = o4.z;
            pbase[(size_t)(1 + c0 + 4 * k + 3) * GHW + mg] = o4.w;
        }
    }
}

// ---------------- combine partials -> att (128 x 3136) ----------------
__global__ __launch_bounds__(256) void combine_kernel(const float* __restrict__ part,
                                                      float* __restrict__ att, int nchunk) {
    int g = blockIdx.x * 256 + threadIdx.x;
    int c0 = blockIdx.y * 8;
    int hd = g / HW, m = g % HW;
    const float* pb = part + g;

    float s = 0.f;
    float a[8];
#pragma unroll
    for (int cc = 0; cc < 8; cc++) a[cc] = 0.f;
    for (int k = 0; k < nchunk; k++) {
        s += pb[(size_t)(k * 33) * GHW];
#pragma unroll
        for (int cc = 0; cc < 8; cc++)
            a[cc] += pb[(size_t)(k * 33 + 1 + c0 + cc) * GHW];
    }
    float inv = 1.f / s;
#pragma unroll
    for (int cc = 0; cc < 8; cc++)
        att[(hd * 32 + c0 + cc) * HW + m] = a[cc] * inv;
}

// ---------------- output 1x1 conv (8 cols / block) ----------------
__global__ __launch_bounds__(128) void out_conv_kernel(const float* __restrict__ att,
                                                       const float* __restrict__ owT,
                                                       const float* __restrict__ ob,
                                                       float* __restrict__ out) {
    int m0 = blockIdx.x * 8;
    int tid = threadIdx.x;
    __shared__ float at[128 * 9];
    for (int e = tid; e < 1024; e += 128) {
        int c = e >> 3, j = e & 7;
        at[c * 9 + j] = att[c * HW + m0 + j];
    }
    __syncthreads();

    float a[8];
#pragma unroll
    for (int j = 0; j < 8; j++) a[j] = 0.f;
    for (int c = 0; c < 128; c++) {
        float w = owT[c * 128 + tid];
#pragma unroll
        for (int j = 0; j < 8; j++) a[j] += w * at[c * 9 + j];
    }
    float b = ob[tid];
#pragma unroll
    for (int j = 0; j < 8; j++) out[tid * HW + m0 + j] = a[j] + b;
}

extern "C" void kernel_launch(void* const* d_in, const int* in_sizes, int n_in,
                              void* d_out, int out_size, void* d_ws, size_t ws_size,
                              hipStream_t stream) {
    const float* x     = (const float*)d_in[0];
    const float* query = (const float*)d_in[1];
    const float* dww   = (const float*)d_in[2];
    const float* dwb   = (const float*)d_in[3];
    const float* lnw   = (const float*)d_in[4];
    const float* lnb   = (const float*)d_in[5];
    const float* pww   = (const float*)d_in[6];
    const float* kw    = (const float*)d_in[7];
    const float* kb    = (const float*)d_in[8];
    const float* vw    = (const float*)d_in[9];
    const float* vb    = (const float*)d_in[10];
    const float* ow    = (const float*)d_in[11];
    const float* ob    = (const float*)d_in[12];
    const float* rpe   = (const float*)d_in[13];
    float* out = (float*)d_out;
    float* ws  = (float*)d_ws;

    prep_kernel<<<dim3(200, 4), 256, 0, stream>>>(kw, vw, ow, rpe,
                                                  ws + OFF_KWT, ws + OFF_VWT, ws + OFF_OWT,
                                                  (float2*)(ws + OFF_TP2));
    tx_kernel<<<dim3(98, 4, 2), 256, 0, stream>>>(x, query, ws + OFF_XT, ws + OFF_QT,
                                                  (ushortT*)(ws + OFF_QBF));
    offset_kernel<<<HW, 128, 0, stream>>>(ws + OFF_QT, dww, dwb, lnw, lnb, pww,
                                          ws + OFF_RWO, (int*)(ws + OFF_AA), ws + OFF_W4);
    sample_kv_kernel<<<392, 128, 0, stream>>>(ws + OFF_XT, ws + OFF_RWO,
                                              ws + OFF_KWT, ws + OFF_VWT, kb, vb,
                                              (ushortT*)(ws + OFF_KBF), (ushortT*)(ws + OFF_VBF));
    attn_kernel<<<dim3(NCHUNK, 25, NHEAD), 256, 0, stream>>>(
        (const ushortT*)(ws + OFF_QBF), (const ushortT*)(ws + OFF_KBF),
        (const ushortT*)(ws + OFF_VBF),
        (const int*)(ws + OFF_AA), (const float4*)(ws + OFF_W4),
        (const float2*)(ws + OFF_TP2), ws + OFF_PART);
    combine_kernel<<<dim3(49, 4), 256, 0, stream>>>(ws + OFF_PART, ws + OFF_ATT, NCHUNK);
    out_conv_kernel<<<392, 128, 0, stream>>>(ws + OFF_ATT, ws + OFF_OWT, ob, out);
}

// Round 6
// 168.638 us; speedup vs baseline: 3.5545x; 1.1593x over previous
//
#include <hip/hip_runtime.h>
#include <hip/hip_bf16.h>
#include <math.h>

#define HH 56
#define WW 56
#define HW 3136
#define NHEAD 4
#define RP 111
#define TP 113                       // padded rpe table dim
#define TPE 12769                    // 113*113
#define SCALE 0.17677669529663687f   // 32^-0.5
#define LOG2E 1.44269504088896f
#define QSC (SCALE * LOG2E)
#define GHW 12544                    // NHEAD*HW
#define NCHUNK 14
#define CLEN 224                     // 3136/14
#define NSTEP 7                      // 224/32

typedef unsigned short ushortT;
typedef __attribute__((ext_vector_type(8))) short short8v;
typedef __attribute__((ext_vector_type(16))) float f32x16;

// ---- ws layout (float offsets) ----
#define OFF_RWO  0u
#define OFF_AA   8192u
#define OFF_W4   12288u
#define OFF_KBF  24832u                      // 4*3136*32 ushort, (h,n,c)
#define OFF_VBF  225536u                     // (h,c,n) bf16
#define OFF_QBF  426240u                     // (h,m,c) bf16, SCALE*log2e folded
#define OFF_KWT  1028352u
#define OFF_VWT  1044736u
#define OFF_OWT  1061120u
#define OFF_XT   1077504u                    // 3136 x 128 f32
#define OFF_QT   1478912u                    // 3136 x 128 f32
#define OFF_TP2  1880320u                    // 4*113*113 float2 (log2e-scaled)
#define OFF_PART 1982976u                    // NCHUNK*33*GHW

__device__ __forceinline__ ushortT f2bf(float f) {
    unsigned u = __float_as_uint(f);
    u += 0x7fffu + ((u >> 16) & 1u);
    return (ushortT)(u >> 16);
}

__device__ __forceinline__ unsigned cvtpk(float lo, float hi) {
    unsigned r;
    asm("v_cvt_pk_bf16_f32 %0, %1, %2" : "=v"(r) : "v"(lo), "v"(hi));
    return r;
}

__device__ __forceinline__ float fexp2(float x) {
    float r;
    asm("v_exp_f32 %0, %1" : "=v"(r) : "v"(x));
    return r;
}

// ------------- prep: weights T, padded log2e-scaled rpe table, x/q transpose -----
__global__ __launch_bounds__(256) void prep_all_kernel(
    const float* __restrict__ kw, const float* __restrict__ vw, const float* __restrict__ ow,
    const float* __restrict__ rpe, const float* __restrict__ x, const float* __restrict__ query,
    float* __restrict__ kwT, float* __restrict__ vwT, float* __restrict__ owT,
    float2* __restrict__ tp2, float* __restrict__ xT, float* __restrict__ qT,
    ushortT* __restrict__ qbf) {
    const int job = blockIdx.y;
    __shared__ float tile[32][33];
    if (job < 3) {
        int i = blockIdx.x * 256 + threadIdx.x;
        if (i >= 16384) return;
        const float* srcw = (job == 0) ? kw : (job == 1) ? vw : ow;
        float* dstw       = (job == 0) ? kwT : (job == 1) ? vwT : owT;
        dstw[(i & 127) * 128 + (i >> 7)] = srcw[i];
    } else if (job == 3) {
        int i = blockIdx.x * 256 + threadIdx.x;
        if (i >= NHEAD * TPE) return;
        int hd = i / TPE, r = i % TPE;
        int py = r / TP, px = r % TP;
        float v0 = 0.f, v1 = 0.f;
        if (py >= 1 && py <= RP) {
            if (px >= 1 && px <= RP) v0 = rpe[hd * RP * RP + (py - 1) * RP + (px - 1)] * LOG2E;
            if (px <= RP - 1)        v1 = rpe[hd * RP * RP + (py - 1) * RP + px] * LOG2E;
        }
        tp2[i] = make_float2(v0, v1);
    } else {
        int bx = blockIdx.x;
        if (bx >= 392) return;
        const float* src = (job == 5) ? query : x;
        float* dst       = (job == 5) ? qT : xT;
        int pt = (bx % 98) * 32, ct = (bx / 98) * 32;
        int jj = threadIdx.x & 31, ii = threadIdx.x >> 5;
#pragma unroll
        for (int r = 0; r < 4; r++)
            tile[ii + r * 8][jj] = src[(ct + ii + r * 8) * HW + pt + jj];
        __syncthreads();
#pragma unroll
        for (int r = 0; r < 4; r++) {
            int p = pt + ii + r * 8, cc = ct + jj;
            float val = tile[jj][ii + r * 8];
            dst[p * 128 + cc] = val;
            if (job == 5)
                qbf[(size_t)((cc >> 5) * HW + p) * 32 + (cc & 31)] = f2bf(val * QSC);
        }
    }
}

__device__ __forceinline__ float wave_sum(float v) {
#pragma unroll
    for (int o = 1; o < 64; o <<= 1) v += __shfl_xor(v, o);
    return v;
}

// ------- offset field: dwconv3x3 + LN + GELU + 1x1 -> rwo + per-n bias prep -------
__global__ __launch_bounds__(128) void offset_kernel(
    const float* __restrict__ qT, const float* __restrict__ dww, const float* __restrict__ dwb,
    const float* __restrict__ lnw, const float* __restrict__ lnb, const float* __restrict__ pww,
    float* __restrict__ rwo, int* __restrict__ aa, float* __restrict__ w4) {
    int p = blockIdx.x;
    int c = threadIdx.x;
    int h = p / WW, w = p % WW;

    float t = dwb[c];
#pragma unroll
    for (int ky = 0; ky < 3; ky++) {
        int yy = h + ky - 1;
        if ((unsigned)yy < (unsigned)HH) {
#pragma unroll
            for (int kx = 0; kx < 3; kx++) {
                int xx = w + kx - 1;
                if ((unsigned)xx < (unsigned)WW)
                    t += qT[(yy * WW + xx) * 128 + c] * dww[c * 9 + ky * 3 + kx];
            }
        }
    }

    __shared__ float sred[4];
    int wid = c >> 6, lane0 = ((c & 63) == 0);

    float s = wave_sum(t);
    if (lane0) sred[wid] = s;
    __syncthreads();
    float mu = (sred[0] + sred[1]) * (1.f / 128.f);
    float d = t - mu;
    __syncthreads();
    s = wave_sum(d * d);
    if (lane0) sred[wid] = s;
    __syncthreads();
    float var = (sred[0] + sred[1]) * (1.f / 128.f);

    float tn = d / sqrtf(var + 1e-5f) * lnw[c] + lnb[c];
    float g = 0.5f * tn * (1.f + erff(tn * 0.70710678118654752f));

    float sy = wave_sum(g * pww[c]);
    float sx = wave_sum(g * pww[128 + c]);
    __syncthreads();
    if (lane0) { sred[wid] = sy; sred[2 + wid] = sx; }
    __syncthreads();
    if (c == 0) {
        float thy = tanhf(sred[0] + sred[1]);
        float thx = tanhf(sred[2] + sred[3]);
        rwo[p * 2]     = thy * (0.5f / 55.f) + ((float)h * (2.f / 55.f) - 1.f);
        rwo[p * 2 + 1] = thx * (0.5f / 55.f) + ((float)w * (2.f / 55.f) - 1.f);
        float ty = 55.f - (float)h - 0.25f * thy;
        float tx = 55.f - (float)w - 0.25f * thx;
        float tyf = floorf(ty), txf = floorf(tx);
        float wy = ty - tyf, wx = tx - txf;
        aa[p] = ((int)tyf) * TP + (int)txf + TP + 1;
        float4 wv;
        wv.x = (1.f - wx) * (1.f - wy);
        wv.y = wx * (1.f - wy);
        wv.z = (1.f - wx) * wy;
        wv.w = wx * wy;
        ((float4*)w4)[p] = wv;
    }
}

// ------- bilinear sample + k/v projection -> bf16 K (h,n,c) and V (h,c,n) --------
__global__ __launch_bounds__(128) void sample_kv_kernel(
    const float* __restrict__ xT, const float* __restrict__ rwo,
    const float* __restrict__ kwT, const float* __restrict__ vwT,
    const float* __restrict__ kb, const float* __restrict__ vb,
    ushortT* __restrict__ kbf, ushortT* __restrict__ vbf) {
    int n0 = blockIdx.x * 8;                 // 392 blocks
    int tid = threadIdx.x;

    __shared__ float xs[128 * 9];
    __shared__ int   cidx[8][4];
    __shared__ float cw[8][4];
    __shared__ ushortT kst[8][128];

    if (tid < 8) {
        int n = n0 + tid;
        float gy = rwo[2 * n], gx = rwo[2 * n + 1];
        float fx = (gx + 1.f) * 27.5f;
        float fy = (gy + 1.f) * 27.5f;
        float x0f = floorf(fx), y0f = floorf(fy);
        float wx = fx - x0f, wy = fy - y0f;
        int x0 = (int)x0f, y0 = (int)y0f;
#pragma unroll
        for (int k = 0; k < 4; k++) {
            int xi = x0 + (k & 1), yi = y0 + (k >> 1);
            float wgt = ((k & 1) ? wx : 1.f - wx) * ((k >> 1) ? wy : 1.f - wy);
            bool v = (xi >= 0) && (xi < WW) && (yi >= 0) && (yi < HH);
            cidx[tid][k] = min(max(yi, 0), HH - 1) * WW + min(max(xi, 0), WW - 1);
            cw[tid][k] = v ? wgt : 0.f;
        }
    }
    __syncthreads();

#pragma unroll
    for (int j = 0; j < 8; j++) {
        float s = cw[j][0] * xT[cidx[j][0] * 128 + tid]
                + cw[j][1] * xT[cidx[j][1] * 128 + tid]
                + cw[j][2] * xT[cidx[j][2] * 128 + tid]
                + cw[j][3] * xT[cidx[j][3] * 128 + tid];
        xs[tid * 9 + j] = s;
    }
    __syncthreads();

    float ak[8], av[8];
#pragma unroll
    for (int j = 0; j < 8; j++) { ak[j] = 0.f; av[j] = 0.f; }
    for (int c = 0; c < 128; c++) {
        float wk = kwT[c * 128 + tid];
        float wv = vwT[c * 128 + tid];
#pragma unroll
        for (int j = 0; j < 8; j++) {
            float xv = xs[c * 9 + j];
            ak[j] += wk * xv;
            av[j] += wv * xv;
        }
    }
    float kbv = kb[tid], vbv = vb[tid];
    int hh = tid >> 5, ch = tid & 31;

    unsigned vp[4];
#pragma unroll
    for (int q = 0; q < 4; q++)
        vp[q] = (unsigned)f2bf(av[2 * q] + vbv) | ((unsigned)f2bf(av[2 * q + 1] + vbv) << 16);
    *(uint4*)(vbf + (size_t)(hh * 32 + ch) * HW + n0) = make_uint4(vp[0], vp[1], vp[2], vp[3]);

#pragma unroll
    for (int j = 0; j < 8; j++) kst[j][tid] = f2bf(ak[j] + kbv);
    __syncthreads();
#pragma unroll
    for (int r = 0; r < 4; r++) {
        int lin = tid + 128 * r;
        int j = lin >> 6, dd = lin & 63;
        int o = 2 * dd;
        unsigned val = *(unsigned*)&kst[j][o];
        int hd2 = o >> 5, ch2 = o & 31;
        ((unsigned*)kbf)[((size_t)(hd2 * HW + n0 + j) * 32 + ch2) >> 1] = val;
    }
}

// -------- MFMA flash attention partials; bias table windowed into LDS ------------
__device__ __forceinline__ void mkw(float pa0, float pa1, float pb0, float pb1, int h,
                                    unsigned &wlo, unsigned &whi) {
    float ta0 = __shfl_xor(pa0, 32);
    float ta1 = __shfl_xor(pa1, 32);
    float tb0 = __shfl_xor(pb0, 32);
    float tb1 = __shfl_xor(pb1, 32);
    wlo = cvtpk(h ? tb0 : pa0, h ? tb1 : pa1);
    whi = cvtpk(h ? pb0 : ta0, h ? pb1 : ta1);
}

__global__ __launch_bounds__(128) void attn_kernel(
    const ushortT* __restrict__ qbf, const ushortT* __restrict__ kbf,
    const ushortT* __restrict__ vbf,
    const int* __restrict__ aa, const float4* __restrict__ w4,
    const float2* __restrict__ tp2g, float* __restrict__ part) {
    const int chunk = blockIdx.x;      // 0..13
    const int mtile = blockIdx.y;      // 0..48
    const int hd = blockIdx.z;         // 0..3
    const int tid = threadIdx.x;       // 128
    const int wv = tid >> 6;
    const int l = tid & 63;
    const int lm = l & 31;
    const int h = l >> 5;

    const int start = chunk * CLEN;
    const int mg = mtile * 64 + wv * 32 + lm;    // 49*64 = 3136, no tail

    __shared__ int aa_s[CLEN];
    __shared__ float4 w4_s[CLEN];
    __shared__ float ubuf[12 * TP * 2];          // union: tpw float2[12*113] / obuf float[2*32*33]
    __shared__ int sred[4];
    float2* tpw = (float2*)ubuf;
    float* obuf = ubuf;

    // load per-n bias data; find accessed row window of the table
    int rmin = 1 << 20, rmax = -(1 << 20);
    for (int i = tid; i < CLEN; i += 128) {
        int av = aa[start + i];
        aa_s[i] = av;
        w4_s[i] = w4[start + i];
        int row = (av * 37118) >> 22;            // av/113 for av < 139810
        rmin = min(rmin, row);
        rmax = max(rmax, row);
    }
#pragma unroll
    for (int o = 1; o < 64; o <<= 1) {
        rmin = min(rmin, __shfl_xor(rmin, o));
        rmax = max(rmax, __shfl_xor(rmax, o));
    }
    if (l == 0) { sred[wv] = rmin; sred[2 + wv] = rmax; }
    __syncthreads();
    rmin = min(sred[0], sred[1]);
    rmax = max(sred[2], sred[3]);
    const int rm0 = (mtile * 64) / WW;
    const int rm1 = (mtile * 64 + 63) / WW;
    const int R0 = rmin + rm0;
    const int NR = rmax + rm1 + 2 - R0;          // <= 8 rows

    const float2* srcw = tp2g + hd * TPE + R0 * TP;
    for (int i = tid; i < NR * TP; i += 128) tpw[i] = srcw[i];
    const int rbase = R0 * TP;
    for (int i = tid; i < CLEN; i += 128) aa_s[i] -= rbase;
    __syncthreads();

    const int base_m = (mg / WW) * TP + (mg % WW);

    const ushortT* qb = qbf + (size_t)(hd * HW + mg) * 32 + h * 8;
    short8v qf0 = *(const short8v*)(qb);
    short8v qf1 = *(const short8v*)(qb + 16);

    const ushortT* kbp = kbf + (size_t)(hd * HW + start) * 32;
    const ushortT* vbp = vbf + (size_t)(hd * 32 + lm) * HW + start;

    f32x16 accO;
#pragma unroll
    for (int i = 0; i < 16; i++) accO[i] = 0.f;
    float ssum = 0.f;

    for (int nt = 0; nt < NSTEP; ++nt) {
        const ushortT* ka = kbp + (size_t)(nt * 32 + lm) * 32 + h * 8;
        short8v kf0 = *(const short8v*)(ka);
        short8v kf1 = *(const short8v*)(ka + 16);
        f32x16 s;
#pragma unroll
        for (int i = 0; i < 16; i++) s[i] = 0.f;
        s = __builtin_amdgcn_mfma_f32_32x32x16_bf16(kf0, qf0, s, 0, 0, 0);
        s = __builtin_amdgcn_mfma_f32_32x32x16_bf16(kf1, qf1, s, 0, 0, 0);

        float p[16];
#pragma unroll
        for (int r = 0; r < 16; ++r) {
            int nl = nt * 32 + (r & 3) + 8 * (r >> 2) + 4 * h;
            int a0 = aa_s[nl] + base_m;
            float4 wvv = w4_s[nl];
            float2 t01 = tpw[a0];
            float2 t23 = tpw[a0 + TP];
            float bias = wvv.x * t01.x + wvv.y * t01.y + wvv.z * t23.x + wvv.w * t23.y;
            float pr = fexp2(s[r] + bias);     // q,table pre-scaled by log2e
            ssum += pr;
            p[r] = pr;
        }

        union { unsigned u[4]; short8v s8; } A0, A1;
        mkw(p[0], p[1], p[4], p[5], h, A0.u[0], A0.u[2]);
        mkw(p[2], p[3], p[6], p[7], h, A0.u[1], A0.u[3]);
        mkw(p[8], p[9], p[12], p[13], h, A1.u[0], A1.u[2]);
        mkw(p[10], p[11], p[14], p[15], h, A1.u[1], A1.u[3]);

        const ushortT* va = vbp + nt * 32 + h * 8;
        short8v vf0 = *(const short8v*)(va);
        short8v vf1 = *(const short8v*)(va + 16);
        accO = __builtin_amdgcn_mfma_f32_32x32x16_bf16(A0.s8, vf0, accO, 0, 0, 0);
        accO = __builtin_amdgcn_mfma_f32_32x32x16_bf16(A1.s8, vf1, accO, 0, 0, 0);
    }

    float st = ssum + __shfl_xor(ssum, 32);

    __syncthreads();                   // done with tpw; reuse as obuf
#pragma unroll
    for (int r = 0; r < 16; ++r) {
        int mr = (r & 3) + 8 * (r >> 2) + 4 * h;
        obuf[(wv * 32 + mr) * 33 + lm] = accO[r];
    }
    __syncthreads();

    float* pbase = part + (size_t)(chunk * 33) * GHW + hd * HW;
    if (h == 0) pbase[mg] = st;
    int c0 = h * 16;
#pragma unroll
    for (int k = 0; k < 4; ++k) {
        float4 o4 = *(const float4*)&obuf[(wv * 32 + lm) * 33 + c0 + 4 * k];
        pbase[(size_t)(1 + c0 + 4 * k + 0) * GHW + mg] = o4.x;
        pbase[(size_t)(1 + c0 + 4 * k + 1) * GHW + mg] = o4.y;
        pbase[(size_t)(1 + c0 + 4 * k + 2) * GHW + mg] = o4.z;
        pbase[(size_t)(1 + c0 + 4 * k + 3) * GHW + mg] = o4.w;
    }
}

// -------- fused combine (normalize over chunks) + output 1x1 conv ----------------
__global__ __launch_bounds__(128) void combine_out_kernel(
    const float* __restrict__ part, const float* __restrict__ owT,
    const float* __restrict__ ob, float* __restrict__ out) {
    int m0 = blockIdx.x * 8;           // 392 blocks
    int tid = threadIdx.x;             // (hd, c)
    int hd = tid >> 5, c = tid & 31;

    __shared__ float at[128 * 9];
    __shared__ float inv_s[4][8];

    float a[8];
#pragma unroll
    for (int j = 0; j < 8; j++) a[j] = 0.f;
    for (int k = 0; k < NCHUNK; k++) {
        const float* p = part + (size_t)(k * 33 + 1 + c) * GHW + hd * HW + m0;
        float4 x0 = *(const float4*)p, x1 = *(const float4*)(p + 4);
        a[0] += x0.x; a[1] += x0.y; a[2] += x0.z; a[3] += x0.w;
        a[4] += x1.x; a[5] += x1.y; a[6] += x1.z; a[7] += x1.w;
    }
    if (c == 0) {
        float sm[8];
#pragma unroll
        for (int j = 0; j < 8; j++) sm[j] = 0.f;
        for (int k = 0; k < NCHUNK; k++) {
            const float* p = part + (size_t)(k * 33) * GHW + hd * HW + m0;
            float4 x0 = *(const float4*)p, x1 = *(const float4*)(p + 4);
            sm[0] += x0.x; sm[1] += x0.y; sm[2] += x0.z; sm[3] += x0.w;
            sm[4] += x1.x; sm[5] += x1.y; sm[6] += x1.z; sm[7] += x1.w;
        }
#pragma unroll
        for (int j = 0; j < 8; j++) inv_s[hd][j] = 1.f / sm[j];
    }
    __syncthreads();
#pragma unroll
    for (int j = 0; j < 8; j++) at[tid * 9 + j] = a[j] * inv_s[hd][j];
    __syncthreads();

    float acc[8];
#pragma unroll
    for (int j = 0; j < 8; j++) acc[j] = 0.f;
    for (int cc = 0; cc < 128; cc++) {
        float w = owT[cc * 128 + tid];
#pragma unroll
        for (int j = 0; j < 8; j++) acc[j] += w * at[cc * 9 + j];
    }
    float b = ob[tid];
#pragma unroll
    for (int j = 0; j < 8; j++) out[tid * HW + m0 + j] = acc[j] + b;
}

extern "C" void kernel_launch(void* const* d_in, const int* in_sizes, int n_in,
                              void* d_out, int out_size, void* d_ws, size_t ws_size,
                              hipStream_t stream) {
    const float* x     = (const float*)d_in[0];
    const float* query = (const float*)d_in[1];
    const float* dww   = (const float*)d_in[2];
    const float* dwb   = (const float*)d_in[3];
    const float* lnw   = (const float*)d_in[4];
    const float* lnb   = (const float*)d_in[5];
    const float* pww   = (const float*)d_in[6];
    const float* kw    = (const float*)d_in[7];
    const float* kb    = (const float*)d_in[8];
    const float* vw    = (const float*)d_in[9];
    const float* vb    = (const float*)d_in[10];
    const float* ow    = (const float*)d_in[11];
    const float* ob    = (const float*)d_in[12];
    const float* rpe   = (const float*)d_in[13];
    float* out = (float*)d_out;
    float* ws  = (float*)d_ws;

    prep_all_kernel<<<dim3(392, 6), 256, 0, stream>>>(
        kw, vw, ow, rpe, x, query,
        ws + OFF_KWT, ws + OFF_VWT, ws + OFF_OWT, (float2*)(ws + OFF_TP2),
        ws + OFF_XT, ws + OFF_QT, (ushortT*)(ws + OFF_QBF));
    offset_kernel<<<HW, 128, 0, stream>>>(ws + OFF_QT, dww, dwb, lnw, lnb, pww,
                                          ws + OFF_RWO, (int*)(ws + OFF_AA), ws + OFF_W4);
    sample_kv_kernel<<<392, 128, 0, stream>>>(ws + OFF_XT, ws + OFF_RWO,
                                              ws + OFF_KWT, ws + OFF_VWT, kb, vb,
                                              (ushortT*)(ws + OFF_KBF), (ushortT*)(ws + OFF_VBF));
    attn_kernel<<<dim3(NCHUNK, 49, NHEAD), 128, 0, stream>>>(
        (const ushortT*)(ws + OFF_QBF), (const ushortT*)(ws + OFF_KBF),
        (const ushortT*)(ws + OFF_VBF),
        (const int*)(ws + OFF_AA), (const float4*)(ws + OFF_W4),
        (const float2*)(ws + OFF_TP2), ws + OFF_PART);
    combine_out_kernel<<<392, 128, 0, stream>>>(ws + OFF_PART, ws + OFF_OWT, ob, out);
}

// Round 7
// 162.462 us; speedup vs baseline: 3.6897x; 1.0380x over previous
//
#include <hip/hip_runtime.h>
#include <hip/hip_bf16.h>
#include <math.h>

#define HH 56
#define WW 56
#define HW 3136
#define NHEAD 4
#define RP 111
#define TP 113                       // padded rpe table dim
#define TPE 12769                    // 113*113
#define SCALE 0.17677669529663687f   // 32^-0.5
#define LOG2E 1.44269504088896f
#define QSC (SCALE * LOG2E)
#define GHW 12544                    // NHEAD*HW
#define NCHUNK 14
#define CLEN 224                     // per-wave n range
#define BLEN 448                     // per-block n range (2 chunks)
#define NSTEP 7                      // 224/32

typedef unsigned short ushortT;
typedef __attribute__((ext_vector_type(8))) short short8v;
typedef __attribute__((ext_vector_type(16))) float f32x16;

// ---- ws layout (float offsets) ----
#define OFF_RWO  0u
#define OFF_AA   8192u
#define OFF_W4   12288u
#define OFF_KBF  24832u                      // 4*3136*32 ushort, (h,n,c)
#define OFF_VBF  225536u                     // (h,c,n) bf16
#define OFF_QBF  426240u                     // (h,m,c) bf16, SCALE*log2e folded
#define OFF_KWT  1028352u
#define OFF_VWT  1044736u
#define OFF_OWT  1061120u
#define OFF_XT   1077504u                    // 3136 x 128 f32
#define OFF_QT   1478912u                    // 3136 x 128 f32
#define OFF_TP2  1880320u                    // 4*113*113 float2 (log2e-scaled)
#define OFF_ATT2 1982976u                    // (hd, m, c) f32 un-normalized, 401408
#define OFF_SUM  2384384u                    // (hd, m) f32, 12544

__device__ __forceinline__ ushortT f2bf(float f) {
    unsigned u = __float_as_uint(f);
    u += 0x7fffu + ((u >> 16) & 1u);
    return (ushortT)(u >> 16);
}

__device__ __forceinline__ unsigned cvtpk(float lo, float hi) {
    unsigned r;
    asm("v_cvt_pk_bf16_f32 %0, %1, %2" : "=v"(r) : "v"(lo), "v"(hi));
    return r;
}

__device__ __forceinline__ float fexp2(float x) {
    float r;
    asm("v_exp_f32 %0, %1" : "=v"(r) : "v"(x));
    return r;
}

// ------------- prep: weights T, padded log2e-scaled rpe table, x/q transpose -----
__global__ __launch_bounds__(256) void prep_all_kernel(
    const float* __restrict__ kw, const float* __restrict__ vw, const float* __restrict__ ow,
    const float* __restrict__ rpe, const float* __restrict__ x, const float* __restrict__ query,
    float* __restrict__ kwT, float* __restrict__ vwT, float* __restrict__ owT,
    float2* __restrict__ tp2, float* __restrict__ xT, float* __restrict__ qT,
    ushortT* __restrict__ qbf) {
    const int job = blockIdx.y;
    __shared__ float tile[32][33];
    if (job < 3) {
        int i = blockIdx.x * 256 + threadIdx.x;
        if (i >= 16384) return;
        const float* srcw = (job == 0) ? kw : (job == 1) ? vw : ow;
        float* dstw       = (job == 0) ? kwT : (job == 1) ? vwT : owT;
        dstw[(i & 127) * 128 + (i >> 7)] = srcw[i];
    } else if (job == 3) {
        int i = blockIdx.x * 256 + threadIdx.x;
        if (i >= NHEAD * TPE) return;
        int hd = i / TPE, r = i % TPE;
        int py = r / TP, px = r % TP;
        float v0 = 0.f, v1 = 0.f;
        if (py >= 1 && py <= RP) {
            if (px >= 1 && px <= RP) v0 = rpe[hd * RP * RP + (py - 1) * RP + (px - 1)] * LOG2E;
            if (px <= RP - 1)        v1 = rpe[hd * RP * RP + (py - 1) * RP + px] * LOG2E;
        }
        tp2[i] = make_float2(v0, v1);
    } else {
        int bx = blockIdx.x;
        if (bx >= 392) return;
        const float* src = (job == 5) ? query : x;
        float* dst       = (job == 5) ? qT : xT;
        int pt = (bx % 98) * 32, ct = (bx / 98) * 32;
        int jj = threadIdx.x & 31, ii = threadIdx.x >> 5;
#pragma unroll
        for (int r = 0; r < 4; r++)
            tile[ii + r * 8][jj] = src[(ct + ii + r * 8) * HW + pt + jj];
        __syncthreads();
#pragma unroll
        for (int r = 0; r < 4; r++) {
            int p = pt + ii + r * 8, cc = ct + jj;
            float val = tile[jj][ii + r * 8];
            dst[p * 128 + cc] = val;
            if (job == 5)
                qbf[(size_t)((cc >> 5) * HW + p) * 32 + (cc & 31)] = f2bf(val * QSC);
        }
    }
}

__device__ __forceinline__ float wave_sum(float v) {
#pragma unroll
    for (int o = 1; o < 64; o <<= 1) v += __shfl_xor(v, o);
    return v;
}

// ------- offset field: dwconv3x3 + LN + GELU + 1x1 -> rwo + per-n bias prep -------
__global__ __launch_bounds__(128) void offset_kernel(
    const float* __restrict__ qT, const float* __restrict__ dww, const float* __restrict__ dwb,
    const float* __restrict__ lnw, const float* __restrict__ lnb, const float* __restrict__ pww,
    float* __restrict__ rwo, int* __restrict__ aa, float* __restrict__ w4) {
    int p = blockIdx.x;
    int c = threadIdx.x;
    int h = p / WW, w = p % WW;

    float t = dwb[c];
#pragma unroll
    for (int ky = 0; ky < 3; ky++) {
        int yy = h + ky - 1;
        if ((unsigned)yy < (unsigned)HH) {
#pragma unroll
            for (int kx = 0; kx < 3; kx++) {
                int xx = w + kx - 1;
                if ((unsigned)xx < (unsigned)WW)
                    t += qT[(yy * WW + xx) * 128 + c] * dww[c * 9 + ky * 3 + kx];
            }
        }
    }

    __shared__ float sred[4];
    int wid = c >> 6, lane0 = ((c & 63) == 0);

    float s = wave_sum(t);
    if (lane0) sred[wid] = s;
    __syncthreads();
    float mu = (sred[0] + sred[1]) * (1.f / 128.f);
    float d = t - mu;
    __syncthreads();
    s = wave_sum(d * d);
    if (lane0) sred[wid] = s;
    __syncthreads();
    float var = (sred[0] + sred[1]) * (1.f / 128.f);

    float tn = d / sqrtf(var + 1e-5f) * lnw[c] + lnb[c];
    float g = 0.5f * tn * (1.f + erff(tn * 0.70710678118654752f));

    float sy = wave_sum(g * pww[c]);
    float sx = wave_sum(g * pww[128 + c]);
    __syncthreads();
    if (lane0) { sred[wid] = sy; sred[2 + wid] = sx; }
    __syncthreads();
    if (c == 0) {
        float thy = tanhf(sred[0] + sred[1]);
        float thx = tanhf(sred[2] + sred[3]);
        rwo[p * 2]     = thy * (0.5f / 55.f) + ((float)h * (2.f / 55.f) - 1.f);
        rwo[p * 2 + 1] = thx * (0.5f / 55.f) + ((float)w * (2.f / 55.f) - 1.f);
        float ty = 55.f - (float)h - 0.25f * thy;
        float tx = 55.f - (float)w - 0.25f * thx;
        float tyf = floorf(ty), txf = floorf(tx);
        float wy = ty - tyf, wx = tx - txf;
        aa[p] = ((int)tyf) * TP + (int)txf + TP + 1;
        float4 wv;
        wv.x = (1.f - wx) * (1.f - wy);
        wv.y = wx * (1.f - wy);
        wv.z = (1.f - wx) * wy;
        wv.w = wx * wy;
        ((float4*)w4)[p] = wv;
    }
}

// ------- bilinear sample + k/v projection -> bf16 K (h,n,c) and V (h,c,n) --------
__global__ __launch_bounds__(128) void sample_kv_kernel(
    const float* __restrict__ xT, const float* __restrict__ rwo,
    const float* __restrict__ kwT, const float* __restrict__ vwT,
    const float* __restrict__ kb, const float* __restrict__ vb,
    ushortT* __restrict__ kbf, ushortT* __restrict__ vbf) {
    int n0 = blockIdx.x * 8;                 // 392 blocks
    int tid = threadIdx.x;

    __shared__ float xs[128 * 9];
    __shared__ int   cidx[8][4];
    __shared__ float cw[8][4];
    __shared__ ushortT kst[8][128];

    if (tid < 8) {
        int n = n0 + tid;
        float gy = rwo[2 * n], gx = rwo[2 * n + 1];
        float fx = (gx + 1.f) * 27.5f;
        float fy = (gy + 1.f) * 27.5f;
        float x0f = floorf(fx), y0f = floorf(fy);
        float wx = fx - x0f, wy = fy - y0f;
        int x0 = (int)x0f, y0 = (int)y0f;
#pragma unroll
        for (int k = 0; k < 4; k++) {
            int xi = x0 + (k & 1), yi = y0 + (k >> 1);
            float wgt = ((k & 1) ? wx : 1.f - wx) * ((k >> 1) ? wy : 1.f - wy);
            bool v = (xi >= 0) && (xi < WW) && (yi >= 0) && (yi < HH);
            cidx[tid][k] = min(max(yi, 0), HH - 1) * WW + min(max(xi, 0), WW - 1);
            cw[tid][k] = v ? wgt : 0.f;
        }
    }
    __syncthreads();

#pragma unroll
    for (int j = 0; j < 8; j++) {
        float s = cw[j][0] * xT[cidx[j][0] * 128 + tid]
                + cw[j][1] * xT[cidx[j][1] * 128 + tid]
                + cw[j][2] * xT[cidx[j][2] * 128 + tid]
                + cw[j][3] * xT[cidx[j][3] * 128 + tid];
        xs[tid * 9 + j] = s;
    }
    __syncthreads();

    float ak[8], av[8];
#pragma unroll
    for (int j = 0; j < 8; j++) { ak[j] = 0.f; av[j] = 0.f; }
    for (int c = 0; c < 128; c++) {
        float wk = kwT[c * 128 + tid];
        float wv = vwT[c * 128 + tid];
#pragma unroll
        for (int j = 0; j < 8; j++) {
            float xv = xs[c * 9 + j];
            ak[j] += wk * xv;
            av[j] += wv * xv;
        }
    }
    float kbv = kb[tid], vbv = vb[tid];
    int hh = tid >> 5, ch = tid & 31;

    unsigned vp[4];
#pragma unroll
    for (int q = 0; q < 4; q++)
        vp[q] = (unsigned)f2bf(av[2 * q] + vbv) | ((unsigned)f2bf(av[2 * q + 1] + vbv) << 16);
    *(uint4*)(vbf + (size_t)(hh * 32 + ch) * HW + n0) = make_uint4(vp[0], vp[1], vp[2], vp[3]);

#pragma unroll
    for (int j = 0; j < 8; j++) kst[j][tid] = f2bf(ak[j] + kbv);
    __syncthreads();
#pragma unroll
    for (int r = 0; r < 4; r++) {
        int lin = tid + 128 * r;
        int j = lin >> 6, dd = lin & 63;
        int o = 2 * dd;
        unsigned val = *(unsigned*)&kst[j][o];
        int hd2 = o >> 5, ch2 = o & 31;
        ((unsigned*)kbf)[((size_t)(hd2 * HW + n0 + j) * 32 + ch2) >> 1] = val;
    }
}

// -------- MFMA flash attention; 4-wave blocks (64m x 448n); atomic merge ---------
__device__ __forceinline__ void mkw(float pa0, float pa1, float pb0, float pb1, int h,
                                    unsigned &wlo, unsigned &whi) {
    float ta0 = __shfl_xor(pa0, 32);
    float ta1 = __shfl_xor(pa1, 32);
    float tb0 = __shfl_xor(pb0, 32);
    float tb1 = __shfl_xor(pb1, 32);
    wlo = cvtpk(h ? tb0 : pa0, h ? tb1 : pa1);
    whi = cvtpk(h ? pb0 : ta0, h ? pb1 : ta1);
}

__global__ __launch_bounds__(256) void attn_kernel(
    const ushortT* __restrict__ qbf, const ushortT* __restrict__ kbf,
    const ushortT* __restrict__ vbf,
    const int* __restrict__ aa, const float4* __restrict__ w4,
    const float2* __restrict__ tp2g, float* __restrict__ att2, float* __restrict__ sums) {
    const int bx = blockIdx.x;         // 0..6  (448-n slabs)
    const int mtile = blockIdx.y;      // 0..48 (64-m tiles)
    const int hd = blockIdx.z;         // 0..3
    const int tid = threadIdx.x;       // 256
    const int wv = tid >> 6;
    const int msub = wv & 1;
    const int csub = wv >> 1;
    const int l = tid & 63;
    const int lm = l & 31;
    const int h = l >> 5;

    const int N0 = bx * BLEN;
    const int m0 = mtile * 64;
    const int mg = m0 + msub * 32 + lm;

    __shared__ int aa_s[BLEN];
    __shared__ float4 w4_s[BLEN];
    __shared__ float2 tpw[12 * TP];

    // analytic table window: 448n aligned to 8 rows; aa padded-rows span
    // [48-h_min, 56-h_min]; + m rows [rm0, rm1] (rm1-rm0 <= 2) + 1 for a0+TP.
    const int h_min = N0 / WW;
    const int rm0 = m0 / WW, rm1 = (m0 + 63) / WW;
    const int R0 = 48 - h_min + rm0;
    const int NR = 10 + rm1 - rm0;               // <= 12
    const int rbase = R0 * TP;

    const float2* srcw = tp2g + hd * TPE + rbase;
    for (int i = tid; i < NR * TP; i += 256) tpw[i] = srcw[i];
    for (int i = tid; i < BLEN; i += 256) {
        aa_s[i] = aa[N0 + i] - rbase;
        w4_s[i] = w4[N0 + i];
    }
    __syncthreads();

    const int base_m = (mg / WW) * TP + (mg % WW);

    const ushortT* qb = qbf + (size_t)(hd * HW + mg) * 32 + h * 8;
    short8v qf0 = *(const short8v*)(qb);
    short8v qf1 = *(const short8v*)(qb + 16);

    const int nwave = N0 + csub * CLEN;
    const ushortT* kbp = kbf + (size_t)(hd * HW + nwave) * 32;
    const ushortT* vbp = vbf + (size_t)(hd * 32 + lm) * HW + nwave;

    f32x16 accO;
#pragma unroll
    for (int i = 0; i < 16; i++) accO[i] = 0.f;
    float ssum = 0.f;

    for (int nt = 0; nt < NSTEP; ++nt) {
        const ushortT* ka = kbp + (size_t)(nt * 32 + lm) * 32 + h * 8;
        short8v kf0 = *(const short8v*)(ka);
        short8v kf1 = *(const short8v*)(ka + 16);
        f32x16 s;
#pragma unroll
        for (int i = 0; i < 16; i++) s[i] = 0.f;
        s = __builtin_amdgcn_mfma_f32_32x32x16_bf16(kf0, qf0, s, 0, 0, 0);
        s = __builtin_amdgcn_mfma_f32_32x32x16_bf16(kf1, qf1, s, 0, 0, 0);

        float p[16];
#pragma unroll
        for (int r = 0; r < 16; ++r) {
            int nl = csub * CLEN + nt * 32 + (r & 3) + 8 * (r >> 2) + 4 * h;
            int a0 = aa_s[nl] + base_m;
            float4 wvv = w4_s[nl];
            float2 t01 = tpw[a0];
            float2 t23 = tpw[a0 + TP];
            float bias = wvv.x * t01.x + wvv.y * t01.y + wvv.z * t23.x + wvv.w * t23.y;
            float pr = fexp2(s[r] + bias);     // q,table pre-scaled by log2e
            ssum += pr;
            p[r] = pr;
        }

        union { unsigned u[4]; short8v s8; } A0, A1;
        mkw(p[0], p[1], p[4], p[5], h, A0.u[0], A0.u[2]);
        mkw(p[2], p[3], p[6], p[7], h, A0.u[1], A0.u[3]);
        mkw(p[8], p[9], p[12], p[13], h, A1.u[0], A1.u[2]);
        mkw(p[10], p[11], p[14], p[15], h, A1.u[1], A1.u[3]);

        const ushortT* va = vbp + nt * 32 + h * 8;
        short8v vf0 = *(const short8v*)(va);
        short8v vf1 = *(const short8v*)(va + 16);
        accO = __builtin_amdgcn_mfma_f32_32x32x16_bf16(A0.s8, vf0, accO, 0, 0, 0);
        accO = __builtin_amdgcn_mfma_f32_32x32x16_bf16(A1.s8, vf1, accO, 0, 0, 0);
    }

    // atomic merge into att2 (hd, m, c) and sums (hd, m)
    float* abase = att2 + (size_t)(hd * HW + m0 + msub * 32) * 32 + lm;
#pragma unroll
    for (int r = 0; r < 16; ++r) {
        int mr = (r & 3) + 8 * (r >> 2) + 4 * h;
        atomicAdd(abase + (size_t)mr * 32, accO[r]);
    }
    float st = ssum + __shfl_xor(ssum, 32);
    if (h == 0) atomicAdd(&sums[hd * HW + mg], st);
}

// -------- normalize att2 + output 1x1 conv ---------------------------------------
__global__ __launch_bounds__(128) void combine_out_kernel(
    const float* __restrict__ att2, const float* __restrict__ sums,
    const float* __restrict__ owT, const float* __restrict__ ob, float* __restrict__ out) {
    int m0 = blockIdx.x * 8;           // 392 blocks
    int tid = threadIdx.x;             // (hd, c)
    int hd = tid >> 5, c = tid & 31;

    __shared__ float at[128 * 9];
    __shared__ float inv_s[4][8];

    if (tid < 32) {
        int hh = tid >> 3, j = tid & 7;
        inv_s[hh][j] = 1.f / sums[hh * HW + m0 + j];
    }
    __syncthreads();

#pragma unroll
    for (int j = 0; j < 8; j++)
        at[tid * 9 + j] = att2[(size_t)(hd * HW + m0 + j) * 32 + c] * inv_s[hd][j];
    __syncthreads();

    float acc[8];
#pragma unroll
    for (int j = 0; j < 8; j++) acc[j] = 0.f;
    for (int cc = 0; cc < 128; cc++) {
        float w = owT[cc * 128 + tid];
#pragma unroll
        for (int j = 0; j < 8; j++) acc[j] += w * at[cc * 9 + j];
    }
    float b = ob[tid];
#pragma unroll
    for (int j = 0; j < 8; j++) out[tid * HW + m0 + j] = acc[j] + b;
}

extern "C" void kernel_launch(void* const* d_in, const int* in_sizes, int n_in,
                              void* d_out, int out_size, void* d_ws, size_t ws_size,
                              hipStream_t stream) {
    const float* x     = (const float*)d_in[0];
    const float* query = (const float*)d_in[1];
    const float* dww   = (const float*)d_in[2];
    const float* dwb   = (const float*)d_in[3];
    const float* lnw   = (const float*)d_in[4];
    const float* lnb   = (const float*)d_in[5];
    const float* pww   = (const float*)d_in[6];
    const float* kw    = (const float*)d_in[7];
    const float* kb    = (const float*)d_in[8];
    const float* vw    = (const float*)d_in[9];
    const float* vb    = (const float*)d_in[10];
    const float* ow    = (const float*)d_in[11];
    const float* ob    = (const float*)d_in[12];
    const float* rpe   = (const float*)d_in[13];
    float* out = (float*)d_out;
    float* ws  = (float*)d_ws;

    prep_all_kernel<<<dim3(392, 6), 256, 0, stream>>>(
        kw, vw, ow, rpe, x, query,
        ws + OFF_KWT, ws + OFF_VWT, ws + OFF_OWT, (float2*)(ws + OFF_TP2),
        ws + OFF_XT, ws + OFF_QT, (ushortT*)(ws + OFF_QBF));
    offset_kernel<<<HW, 128, 0, stream>>>(ws + OFF_QT, dww, dwb, lnw, lnb, pww,
                                          ws + OFF_RWO, (int*)(ws + OFF_AA), ws + OFF_W4);
    sample_kv_kernel<<<392, 128, 0, stream>>>(ws + OFF_XT, ws + OFF_RWO,
                                              ws + OFF_KWT, ws + OFF_VWT, kb, vb,
                                              (ushortT*)(ws + OFF_KBF), (ushortT*)(ws + OFF_VBF));
    hipMemsetAsync(ws + OFF_ATT2, 0, (size_t)(401408 + 12544) * 4, stream);
    attn_kernel<<<dim3(7, 49, NHEAD), 256, 0, stream>>>(
        (const ushortT*)(ws + OFF_QBF), (const ushortT*)(ws + OFF_KBF),
        (const ushortT*)(ws + OFF_VBF),
        (const int*)(ws + OFF_AA), (const float4*)(ws + OFF_W4),
        (const float2*)(ws + OFF_TP2), ws + OFF_ATT2, ws + OFF_SUM);
    combine_out_kernel<<<392, 128, 0, stream>>>(ws + OFF_ATT2, ws + OFF_SUM,
                                                ws + OFF_OWT, ob, out);
}